// Round 7
// baseline (811.937 us; speedup 1.0000x reference)
//
#include <hip/hip_runtime.h>
#include <hip/hip_bf16.h>
#include <stdint.h>

// ---------- constants ----------
#define BATCH 64
#define CC 384
#define NHEAD 12
#define KD 32
#define NTOK 49
#define LL 784
#define MTOT 50176        // BATCH*LL = 1024 windows * 49
#define HID 1536
#define QKV_OUT 1152
#define SCALE 0.17677669529663687f
#define EPS 1e-5f

typedef __bf16 bf16x8 __attribute__((ext_vector_type(8)));
typedef float f32x4 __attribute__((ext_vector_type(4)));

__device__ __forceinline__ float bf2f(unsigned short u) {
  union { unsigned int u; float f; } cv; cv.u = ((unsigned int)u) << 16; return cv.f;
}
__device__ __forceinline__ unsigned short f2bf(float f) {
  union { float f; unsigned int u; } cv; cv.f = f;
  unsigned int r = cv.u + 0x7FFFu + ((cv.u >> 16) & 1u);
  return (unsigned short)(r >> 16);
}
__device__ __forceinline__ void gl_lds16(const unsigned short* g, unsigned short* l) {
  __builtin_amdgcn_global_load_lds(
      (const __attribute__((address_space(1))) unsigned int*)g,
      (__attribute__((address_space(3))) unsigned int*)l, 16, 0, 0);
}

// ---------- dtype detection (bf16 vs fp32 wire format) ----------
__global__ void detect_kernel(const unsigned short* __restrict__ x, int* flag) {
  __shared__ int cnt;
  if (threadIdx.x == 0) cnt = 0;
  __syncthreads();
  int c = 0;
  for (int i = threadIdx.x; i < 4096; i += 256) {
    if (((x[i] >> 7) & 0xFF) == 0xFF) c++;
  }
  atomicAdd(&cnt, c);
  __syncthreads();
  if (threadIdx.x == 0) *flag = (cnt > 0) ? 1 : 0;
}

// ---------- input canonicalization (vectorized) ----------
struct CvtArgs {
  const void* src[19];
  unsigned int n[19];
  unsigned int off[19];
};
__global__ __launch_bounds__(256) void convert_kernel(
    CvtArgs a, unsigned short* __restrict__ dst, const int* __restrict__ flag) {
  const int which = blockIdx.y;
  const unsigned int nn = a.n[which];
  unsigned short* d = dst + a.off[which];
  const unsigned int stride = gridDim.x * blockDim.x;
  const unsigned int idx = blockIdx.x * blockDim.x + threadIdx.x;
  const unsigned int ng = nn >> 3;
  if (*flag) {
    const float* s = (const float*)a.src[which];
    for (unsigned int g = idx; g < ng; g += stride) {
      const float4 f0 = ((const float4*)s)[g * 2];
      const float4 f1 = ((const float4*)s)[g * 2 + 1];
      ushort4 lo, hi;
      lo.x = f2bf(f0.x); lo.y = f2bf(f0.y); lo.z = f2bf(f0.z); lo.w = f2bf(f0.w);
      hi.x = f2bf(f1.x); hi.y = f2bf(f1.y); hi.z = f2bf(f1.z); hi.w = f2bf(f1.w);
      ((ushort4*)d)[g * 2] = lo;
      ((ushort4*)d)[g * 2 + 1] = hi;
    }
    for (unsigned int i = ng * 8 + idx; i < nn; i += stride) d[i] = f2bf(s[i]);
  } else {
    const unsigned short* s = (const unsigned short*)a.src[which];
    for (unsigned int g = idx; g < ng; g += stride)
      ((uint4*)d)[g] = ((const uint4*)s)[g];
    for (unsigned int i = ng * 8 + idx; i < nn; i += stride) d[i] = s[i];
  }
}

// ---------- bias table precompute: bias_full[h][n][m] fp32 ----------
__global__ __launch_bounds__(256) void bias_kernel(
    const unsigned short* __restrict__ cAb, const int* __restrict__ bias_idxs,
    float* __restrict__ bias_full) {
  const int h = blockIdx.x;
  for (int i = threadIdx.x; i < NTOK * NTOK; i += 256)
    bias_full[h * NTOK * NTOK + i] = bf2f(cAb[h * NTOK + bias_idxs[i]]);
}

// ---------- conv/BN table precompute: cwT[t][c] bf16, bn scale/shift fp32 ----------
__global__ __launch_bounds__(384) void prep_kernel(
    const unsigned short* __restrict__ cw, const unsigned short* __restrict__ bg,
    const unsigned short* __restrict__ bb, const unsigned short* __restrict__ bm,
    const unsigned short* __restrict__ bv,
    unsigned short* __restrict__ cwT, float* __restrict__ bnsc, float* __restrict__ bnsh) {
  const int c = threadIdx.x;
  const float sc = bf2f(bg[c]) * rsqrtf(bf2f(bv[c]) + EPS);
  bnsc[c] = sc;
  bnsh[c] = bf2f(bb[c]) - bf2f(bm[c]) * sc;
  #pragma unroll
  for (int t = 0; t < 9; ++t) cwT[t * CC + c] = cw[c * 9 + t];
}

// ---------- LayerNorm + window gather (pre-attention) ----------
__global__ __launch_bounds__(128) void ln_kernel(
    const unsigned short* __restrict__ x, const unsigned short* __restrict__ g,
    const unsigned short* __restrict__ b, unsigned short* __restrict__ out) {
  const int tid = threadIdx.x;
  int wi = blockIdx.y, n = blockIdx.x;
  int bb = wi >> 4, wb = wi & 15;
  int nh_i = wb >> 2, nw_i = wb & 3;
  int hs = n / 7, wsx = n - hs * 7;
  int l = nh_i * 196 + hs * 28 + nw_i * 7 + wsx;
  size_t src_row = (size_t)bb * LL + l;
  size_t dst_row = (size_t)wi * NTOK + n;
  const unsigned short* xr = x + src_row * CC;
  float vals[3]; float s = 0.f, sq = 0.f;
  for (int j = 0; j < 3; ++j) {
    vals[j] = bf2f(xr[tid + 128 * j]);
    s += vals[j]; sq += vals[j] * vals[j];
  }
  for (int off = 32; off; off >>= 1) { s += __shfl_xor(s, off); sq += __shfl_xor(sq, off); }
  __shared__ float red[4];
  const int wv = tid >> 6;
  if ((tid & 63) == 0) { red[wv] = s; red[2 + wv] = sq; }
  __syncthreads();
  float tot = red[0] + red[1], totq = red[2] + red[3];
  float mean = tot * (1.f / CC);
  float var = totq * (1.f / CC) - mean * mean;
  float inv = rsqrtf(var + EPS);
  unsigned short* orow = out + dst_row * CC;
  for (int j = 0; j < 3; ++j) {
    int c = tid + 128 * j;
    float y = (vals[j] - mean) * inv * bf2f(g[c]) + bf2f(b[c]);
    orow[c] = f2bf(y);
  }
}

// ---------- GEMM: 128x128 tile, 4 waves, 4x4 acc, BK=32 ----------
// R7 structural change: B (weights, L2/L1-resident) is loaded DIRECTLY
// global->register per lane, double-buffered in two NAMED frag sets
// (rule #20) via an unroll-by-2 loop. Only A goes through LDS.
// Rationale (R6 post-mortem): the CU LDS data port was ~saturated
// (reads 32KB + DMA 16KB per block-iter ~ the whole iteration wall);
// removing B halves LDS-port traffic and staging DMA, and cuts LDS/block
// 48->24 KB.
// vmcnt bookkeeping (counter is in-order): per iter t issue B(t+1):4 then
// stage A(t+2):2 -> at iter-t wait, outstanding = A(t):2,B(t):4,A(t+1):2;
// vmcnt(2) retires exactly A(t)+B(t), keeps A(t+1) in flight.
// Prologue: stage A(0); loadB(0); stage A(1)  (preserves in-order rule).
// Single barrier per K-step (R6): WAR on A-buffers safe because readers
// of buf[(t-1)%3] retired (lgkmcnt(0)) before this iter's barrier and the
// overwrite stages after it.
// Grid: 1D, XCD-chunked bijective remap (m204) + N-fastest tile order
// (R4: fc2 FETCH 269 -> 117 MB; keep).
enum { EP_PLAIN = 0, EP_GELU = 1, EP_WINRES = 2, EP_RES2 = 3 };

template <int EP>
__global__ __launch_bounds__(256) void gemm128(
    const unsigned short* __restrict__ A, const unsigned short* __restrict__ W,
    const unsigned short* __restrict__ bias, const unsigned short* __restrict__ res,
    void* __restrict__ outp, int K, int N, int m_off, const int* __restrict__ flagp,
    int Nt) {
  __shared__ __align__(16) unsigned short lds[3 * 4096];  // 3 x (A 128x32) = 24KB
  const int tid = threadIdx.x;
  const int lane = tid & 63;
  const int wave = tid >> 6;
  // --- XCD-chunked bijective remap (m204), then N-fastest tile order ---
  const int nwg = gridDim.x;
  const int id = blockIdx.x;
  const int q8 = nwg >> 3, r8 = nwg & 7;
  const int xcd = id & 7, rank = id >> 3;
  const int wgid = (xcd < r8 ? xcd * (q8 + 1) : r8 * (q8 + 1) + (xcd - r8) * q8) + rank;
  const int bm = (wgid / Nt) * 128;
  const int bn = (wgid - (wgid / Nt) * Nt) * 128;
  const int wm = (wave >> 1) * 64;
  const int wn = (wave & 1) * 64;
  // A staging: row = tid>>2 (0..63, +64 second call), granule c = tid&3.
  // source col XOR-permuted with p(row); LDS dest linear (tid*8).
  const int srow = tid >> 2;
  const int sr15 = srow & 15;
  const int sp = (sr15 + (sr15 >> 2)) & 3;
  const int s_col = ((tid & 3) ^ sp) * 8;   // swizzled source col (shorts)
  const unsigned short* Ap0 = A + (size_t)(bm + srow) * K + s_col;
  const size_t rstep = (size_t)64 * K;
  f32x4 acc[4][4] = {};
  const int fr = lane & 15;
  const int quad = lane >> 4;
  const int nt = K >> 5;   // K % 64 == 0 here (384, 1536) -> nt even (12/48)
  const int rp = (fr + (fr >> 2)) & 3;
  const int cg = (quad ^ rp) * 8;          // A read granule (matches sp at row&15==fr)
  // B direct-from-global per-lane base: row bn+wn+j*16+fr, k = quad*8 within tile
  const unsigned short* WB = W + (size_t)(bn + wn + fr) * K + quad * 8;

  int b = 0;
  auto stage = [&](int bsel, int t) {
    const unsigned short* ap = Ap0 + (size_t)t * 32;
    unsigned short* al = lds + bsel * 4096 + tid * 8;
    gl_lds16(ap, al);
    gl_lds16(ap + rstep, al + 2048);
  };
  auto loadB = [&](bf16x8 (&dst)[4], int t) {
    #pragma unroll
    for (int j = 0; j < 4; ++j)
      dst[j] = *(const bf16x8*)(WB + (size_t)(j * 16) * K + (size_t)t * 32);
  };
  bf16x8 bA[4], bB[4];

  // prologue (order matters for in-order vmcnt accounting)
  stage(0, 0);       // A(0): 2 loads
  loadB(bA, 0);      // B(0): 4 loads
  stage(1, 1);       // A(1): 2 loads
  auto body = [&](bf16x8 (&bcur)[4], bf16x8 (&bnxt)[4], int t) {
    // outstanding here (oldest first): A(t):2, B(t):4, A(t+1):2
    if (t + 1 < nt) asm volatile("s_waitcnt vmcnt(2)" ::: "memory");
    else            asm volatile("s_waitcnt vmcnt(0)" ::: "memory");
    __builtin_amdgcn_s_barrier();            // A tile t resident for all waves
    __builtin_amdgcn_sched_barrier(0);
    if (t + 1 < nt) loadB(bnxt, t + 1);      // B(t+1): 4 loads
    if (t + 2 < nt) stage(b ? b - 1 : 2, t + 2);   // A(t+2): 2 loads
    const unsigned short* Ab = lds + b * 4096;
    bf16x8 af[4];
    #pragma unroll
    for (int i = 0; i < 4; ++i)
      af[i] = *(const bf16x8*)(Ab + (wm + i * 16 + fr) * 32 + cg);
    #pragma unroll
    for (int i = 0; i < 4; ++i)
      #pragma unroll
      for (int j = 0; j < 4; ++j)
        acc[i][j] = __builtin_amdgcn_mfma_f32_16x16x32_bf16(af[i], bcur[j], acc[i][j], 0, 0, 0);
    asm volatile("s_waitcnt lgkmcnt(0)" ::: "memory");  // my reads of buf t retired
    __builtin_amdgcn_sched_barrier(0);
    b = (b == 2) ? 0 : b + 1;
  };
  for (int t = 0; t < nt; t += 2) {
    body(bA, bB, t);
    body(bB, bA, t + 1);
  }

  int isf32 = 0;
  if (EP == EP_RES2) isf32 = *flagp;
  const int qr = (lane >> 4) * 4;
  float bvs[4];
  #pragma unroll
  for (int tj = 0; tj < 4; ++tj) bvs[tj] = bf2f(bias[bn + wn + tj * 16 + fr]);
  #pragma unroll
  for (int ti = 0; ti < 4; ++ti) {
    #pragma unroll
    for (int r = 0; r < 4; ++r) {
      const int mr = bm + wm + ti * 16 + qr + r;
      size_t rowbase;
      if (EP == EP_WINRES) {
        int wi = mr / 49; int nt2 = mr - wi * 49;
        int bb = wi >> 4; int wb = wi & 15;
        int nh_i = wb >> 2; int nw_i = wb & 3;
        int hs = nt2 / 7; int wsx = nt2 - hs * 7;
        int l = nh_i * 196 + hs * 28 + nw_i * 7 + wsx;
        rowbase = ((size_t)bb * LL + l) * CC;
      } else if (EP == EP_RES2) {
        rowbase = (size_t)(mr + m_off) * N;
      } else {
        rowbase = (size_t)mr * N;
      }
      #pragma unroll
      for (int tj = 0; tj < 4; ++tj) {
        const int n = bn + wn + tj * 16 + fr;
        float v = acc[ti][tj][r] + bvs[tj];
        if (EP == EP_GELU) {
          // gelu(x) = x * sigmoid(1.59576912x + 0.07135482x^3)
          const float t2 = v * (1.5957691216f + 0.0713548162f * v * v);
          v = __fdividef(v, 1.0f + __expf(-t2));
          ((unsigned short*)outp)[rowbase + n] = f2bf(v);
        } else if (EP == EP_WINRES) {
          size_t idx = rowbase + n;
          v += bf2f(res[idx]);
          ((unsigned short*)outp)[idx] = f2bf(v);
        } else if (EP == EP_RES2) {
          size_t idx = rowbase + n;
          v += bf2f(res[idx]);
          if (isf32) ((float*)outp)[idx] = v;
          else       ((unsigned short*)outp)[idx] = f2bf(v);
        } else {
          ((unsigned short*)outp)[rowbase + n] = f2bf(v);
        }
      }
    }
  }
}

// ---------- MFMA windowed attention: one WAVE per (window, head) ----------
__global__ __launch_bounds__(64) void attn_mfma(
    const unsigned short* __restrict__ qkv, const float* __restrict__ bias_full,
    unsigned short* __restrict__ o, int wi_off) {
  __shared__ __align__(16) unsigned short Pl[64 * 72];
  __shared__ __align__(16) unsigned short vT[32 * 72];
  const int wi = blockIdx.x, h = blockIdx.y;
  const int lane = threadIdx.x;
  const int l15 = lane & 15;
  const int quad = lane >> 4;
  const unsigned short* base = qkv + (size_t)wi * NTOK * QKV_OUT + h * 96;

  bf16x8 qf[4], kf[4];
  #pragma unroll
  for (int i = 0; i < 4; ++i) {
    const int n = i * 16 + l15;
    if (n < NTOK) {
      const unsigned short* p = base + (size_t)n * QKV_OUT + quad * 8;
      qf[i] = *(const bf16x8*)(p);
      kf[i] = *(const bf16x8*)(p + 32);
    } else {
      qf[i] = (bf16x8)0; kf[i] = (bf16x8)0;
    }
  }

  for (int idx = lane; idx < 32 * 72; idx += 64) vT[idx] = 0;
  __syncthreads();
  for (int idx = lane; idx < NTOK * KD; idx += 64) {
    const int m = idx >> 5, d = idx & 31;
    vT[d * 72 + m] = base[(size_t)m * QKV_OUT + 64 + d];
  }

  f32x4 acc[4][4] = {};
  #pragma unroll
  for (int i = 0; i < 4; ++i)
    #pragma unroll
    for (int j = 0; j < 4; ++j)
      acc[i][j] = __builtin_amdgcn_mfma_f32_16x16x32_bf16(qf[i], kf[j], acc[i][j], 0, 0, 0);

  const float* bh = bias_full + h * NTOK * NTOK;
  float rinv[4][4];
  #pragma unroll
  for (int i = 0; i < 4; ++i) {
    #pragma unroll
    for (int r = 0; r < 4; ++r) {
      const int n = i * 16 + quad * 4 + r;
      float sv[4];
      #pragma unroll
      for (int j = 0; j < 4; ++j) {
        const int m = j * 16 + l15;
        float s = acc[i][j][r] * SCALE;
        if (n < NTOK && m < NTOK) s += bh[n * NTOK + m];
        if (m >= NTOK) s = -1e30f;
        sv[j] = s;
      }
      float mx = fmaxf(fmaxf(sv[0], sv[1]), fmaxf(sv[2], sv[3]));
      #pragma unroll
      for (int t = 1; t < 16; t <<= 1) mx = fmaxf(mx, __shfl_xor(mx, t));
      float sum = 0.f;
      #pragma unroll
      for (int j = 0; j < 4; ++j) {
        const float p = __expf(sv[j] - mx);
        sum += p;
        Pl[n * 72 + j * 16 + l15] = f2bf(p);
      }
      #pragma unroll
      for (int t = 1; t < 16; t <<= 1) sum += __shfl_xor(sum, t);
      rinv[i][r] = 1.f / sum;
    }
  }
  __syncthreads();

  f32x4 acc2[4][2] = {};
  #pragma unroll
  for (int kk = 0; kk < 2; ++kk) {
    bf16x8 pf[4], vf[2];
    #pragma unroll
    for (int i = 0; i < 4; ++i)
      pf[i] = *(const bf16x8*)(Pl + (i * 16 + l15) * 72 + kk * 32 + quad * 8);
    #pragma unroll
    for (int jd = 0; jd < 2; ++jd)
      vf[jd] = *(const bf16x8*)(vT + (jd * 16 + l15) * 72 + kk * 32 + quad * 8);
    #pragma unroll
    for (int i = 0; i < 4; ++i)
      #pragma unroll
      for (int jd = 0; jd < 2; ++jd)
        acc2[i][jd] = __builtin_amdgcn_mfma_f32_16x16x32_bf16(pf[i], vf[jd], acc2[i][jd], 0, 0, 0);
  }

  #pragma unroll
  for (int i = 0; i < 4; ++i) {
    #pragma unroll
    for (int r = 0; r < 4; ++r) {
      const int n = i * 16 + quad * 4 + r;
      if (n < NTOK) {
        const float ri = rinv[i][r];
        #pragma unroll
        for (int jd = 0; jd < 2; ++jd) {
          const int d = jd * 16 + l15;
          o[((size_t)(wi_off + wi) * NTOK + n) * CC + h * KD + d] = f2bf(acc2[i][jd][r] * ri);
        }
      }
    }
  }
}

// ---------- fused depthwise 3x3 conv + BN + LN_m ----------
__global__ __launch_bounds__(384) void conv_bn_ln(
    const unsigned short* __restrict__ x1, const unsigned short* __restrict__ cwT,
    const float* __restrict__ bnsc, const float* __restrict__ bnsh,
    const unsigned short* __restrict__ mg, const unsigned short* __restrict__ mb,
    unsigned short* __restrict__ x2, unsigned short* __restrict__ xm) {
  __shared__ float rs[8][48], rq[8][48];
  const int tid = threadIdx.x;
  const int pos = tid / 48;
  const int c8 = tid - pos * 48;
  const int c0 = c8 * 8;
  const int hw = blockIdx.x * 8 + pos;
  const int b = blockIdx.y;
  const int h = hw / 28, w = hw - h * 28;
  float acc[8] = {};
  #pragma unroll
  for (int t = 0; t < 9; ++t) {
    const int dh = t / 3 - 1, dw = t % 3 - 1;
    const int hh = h + dh, ww = w + dw;
    if (hh >= 0 && hh < 28 && ww >= 0 && ww < 28) {
      const uint4 xv = *(const uint4*)(x1 + ((size_t)b * LL + hh * 28 + ww) * CC + c0);
      const uint4 wv = *(const uint4*)(cwT + t * CC + c0);
      const unsigned short* xp = (const unsigned short*)&xv;
      const unsigned short* wp = (const unsigned short*)&wv;
      #pragma unroll
      for (int k = 0; k < 8; ++k) acc[k] += bf2f(xp[k]) * bf2f(wp[k]);
    }
  }
  const float4 sc0 = *(const float4*)(bnsc + c0);
  const float4 sc1 = *(const float4*)(bnsc + c0 + 4);
  const float4 sh0 = *(const float4*)(bnsh + c0);
  const float4 sh1 = *(const float4*)(bnsh + c0 + 4);
  float y[8];
  y[0] = acc[0] * sc0.x + sh0.x; y[1] = acc[1] * sc0.y + sh0.y;
  y[2] = acc[2] * sc0.z + sh0.z; y[3] = acc[3] * sc0.w + sh0.w;
  y[4] = acc[4] * sc1.x + sh1.x; y[5] = acc[5] * sc1.y + sh1.y;
  y[6] = acc[6] * sc1.z + sh1.z; y[7] = acc[7] * sc1.w + sh1.w;
  ushort4 pk0, pk1;
  pk0.x = f2bf(y[0]); pk0.y = f2bf(y[1]); pk0.z = f2bf(y[2]); pk0.w = f2bf(y[3]);
  pk1.x = f2bf(y[4]); pk1.y = f2bf(y[5]); pk1.z = f2bf(y[6]); pk1.w = f2bf(y[7]);
  const size_t row = ((size_t)b * LL + hw) * CC + c0;
  *(ushort4*)(x2 + row) = pk0;
  *(ushort4*)(x2 + row + 4) = pk1;
  float s = 0.f, q = 0.f;
  #pragma unroll
  for (int k = 0; k < 8; ++k) { s += y[k]; q += y[k] * y[k]; }
  rs[pos][c8] = s; rq[pos][c8] = q;
  __syncthreads();
  float tot = 0.f, tq = 0.f;
  #pragma unroll 8
  for (int i = 0; i < 48; ++i) { tot += rs[pos][i]; tq += rq[pos][i]; }
  const float mean = tot * (1.f / CC);
  const float var = tq * (1.f / CC) - mean * mean;
  const float inv = rsqrtf(var + EPS);
  const uint4 gv = *(const uint4*)(mg + c0);
  const uint4 bv = *(const uint4*)(mb + c0);
  const unsigned short* gp = (const unsigned short*)&gv;
  const unsigned short* bp = (const unsigned short*)&bv;
  ushort4 lo, hi;
  unsigned short outv[8];
  #pragma unroll
  for (int k = 0; k < 8; ++k)
    outv[k] = f2bf((y[k] - mean) * inv * bf2f(gp[k]) + bf2f(bp[k]));
  lo.x = outv[0]; lo.y = outv[1]; lo.z = outv[2]; lo.w = outv[3];
  hi.x = outv[4]; hi.y = outv[5]; hi.z = outv[6]; hi.w = outv[7];
  *(ushort4*)(xm + row) = lo;
  *(ushort4*)(xm + row + 4) = hi;
}

// ---------- launch ----------
extern "C" void kernel_launch(void* const* d_in, const int* in_sizes, int n_in,
                              void* d_out, int out_size, void* d_ws, size_t ws_size,
                              hipStream_t stream) {
  int* flag = (int*)d_ws;
  unsigned short* base = (unsigned short*)d_ws;

  CvtArgs args;
  size_t cur = 32;
  size_t off[19];
  for (int i = 0; i < 19; ++i) {
    off[i] = cur;
    args.src[i] = d_in[i];
    args.n[i] = (unsigned int)in_sizes[i];
    args.off[i] = (unsigned int)cur;
    cur += ((size_t)in_sizes[i] + 63) & ~(size_t)63;
  }
  const unsigned short* cx   = base + off[0];
  const unsigned short* cgA  = base + off[1];
  const unsigned short* cbA  = base + off[2];
  const unsigned short* cQw  = base + off[3];
  const unsigned short* cQb  = base + off[4];
  const unsigned short* cAb  = base + off[5];
  const unsigned short* cPw  = base + off[6];
  const unsigned short* cPb  = base + off[7];
  const unsigned short* cCw  = base + off[8];
  const unsigned short* cBg  = base + off[9];
  const unsigned short* cBb  = base + off[10];
  const unsigned short* cBm  = base + off[11];
  const unsigned short* cBv  = base + off[12];
  const unsigned short* cMg  = base + off[13];
  const unsigned short* cMb  = base + off[14];
  const unsigned short* cF1w = base + off[15];
  const unsigned short* cF1b = base + off[16];
  const unsigned short* cF2w = base + off[17];
  const unsigned short* cF2b = base + off[18];
  const int* bias_idxs = (const int*)d_in[19];

  const size_t SZ = (size_t)MTOT * CC;             // 19267584 elems
  // chunking: merge M-halves into one launch if workspace permits.
  const size_t need_full_bytes =
      (cur + SZ + (size_t)MTOT * HID) * 2 + 512 * 1024;
  const int nchunk = (ws_size >= need_full_bytes) ? 1 : 2;
  const int MC = MTOT / nchunk;                    // GEMM rows per chunk
  const int WC = 1024 / nchunk;                    // windows per chunk
  const size_t buf2_cap = (size_t)MC * HID;

  unsigned short* o_buf = base + cur;               // attn out o; later xm
  unsigned short* buf2  = o_buf + SZ;               // qkv chunk / h chunk
  unsigned short* x2    = base + off[0];            // conv+BN out overwrites spent cx
  float* bias_full = (float*)(buf2 + buf2_cap);     // [12][49][49] f32
  unsigned short* cwT = (unsigned short*)(bias_full + 12 * NTOK * NTOK);  // [9][384] bf16
  float* bnsc = (float*)(cwT + 9 * CC);
  float* bnsh = bnsc + CC;

  unsigned short* xn = (unsigned short*)d_out;

  // 0. dtype detect + canonicalize + tables
  detect_kernel<<<1, 256, 0, stream>>>((const unsigned short*)d_in[0], flag);
  convert_kernel<<<dim3(512, 19), 256, 0, stream>>>(args, base, flag);
  bias_kernel<<<NHEAD, 256, 0, stream>>>(cAb, bias_idxs, bias_full);
  prep_kernel<<<1, 384, 0, stream>>>(cCw, cBg, cBb, cBm, cBv, cwT, bnsc, bnsh);

  // 1. window partition + LN_a -> xn (d_out)
  ln_kernel<<<dim3(49, 1024), 128, 0, stream>>>(cx, cgA, cbA, xn);

  // 2+3. qkv projection + MFMA attention
  for (int c = 0; c < nchunk; ++c) {
    gemm128<EP_PLAIN><<<(MC / 128) * (QKV_OUT / 128), 256, 0, stream>>>(
        xn + (size_t)c * MC * CC, cQw, cQb, nullptr, buf2, CC, QKV_OUT, 0, nullptr,
        QKV_OUT / 128);
    attn_mfma<<<dim3(WC, NHEAD), 64, 0, stream>>>(buf2, bias_full, o_buf, c * WC);
  }

  // 4. proj + un-window + residual(x) -> x1 (d_out)
  gemm128<EP_WINRES><<<(MTOT / 128) * (CC / 128), 256, 0, stream>>>(
      o_buf, cPw, cPb, cx, d_out, CC, CC, 0, nullptr, CC / 128);

  // 5. fused conv + BN + LN_m -> x2 (residual) and xm (o_buf, fc1 input)
  conv_bn_ln<<<dim3(98, BATCH), 384, 0, stream>>>(
      (const unsigned short*)d_out, cwT, bnsc, bnsh, cMg, cMb, x2, o_buf);

  // 6+7. MLP; fc2 writes final output
  for (int c = 0; c < nchunk; ++c) {
    gemm128<EP_GELU><<<(MC / 128) * (HID / 128), 256, 0, stream>>>(
        o_buf + (size_t)c * MC * CC, cF1w, cF1b, nullptr, buf2, CC, HID, 0, nullptr,
        HID / 128);
    gemm128<EP_RES2><<<(MC / 128) * (CC / 128), 256, 0, stream>>>(
        buf2, cF2w, cF2b, x2, d_out, HID, CC, c * MC, flag, CC / 128);
  }
}

// Round 8
// 777.059 us; speedup vs baseline: 1.0449x; 1.0449x over previous
//
#include <hip/hip_runtime.h>
#include <hip/hip_bf16.h>
#include <stdint.h>

// ---------- constants ----------
#define BATCH 64
#define CC 384
#define NHEAD 12
#define KD 32
#define NTOK 49
#define LL 784
#define MTOT 50176        // BATCH*LL = 1024 windows * 49
#define HID 1536
#define QKV_OUT 1152
#define SCALE 0.17677669529663687f
#define EPS 1e-5f

typedef __bf16 bf16x8 __attribute__((ext_vector_type(8)));
typedef float f32x4 __attribute__((ext_vector_type(4)));

__device__ __forceinline__ float bf2f(unsigned short u) {
  union { unsigned int u; float f; } cv; cv.u = ((unsigned int)u) << 16; return cv.f;
}
__device__ __forceinline__ unsigned short f2bf(float f) {
  union { float f; unsigned int u; } cv; cv.f = f;
  unsigned int r = cv.u + 0x7FFFu + ((cv.u >> 16) & 1u);
  return (unsigned short)(r >> 16);
}
__device__ __forceinline__ void gl_lds16(const unsigned short* g, unsigned short* l) {
  __builtin_amdgcn_global_load_lds(
      (const __attribute__((address_space(1))) unsigned int*)g,
      (__attribute__((address_space(3))) unsigned int*)l, 16, 0, 0);
}

// ---------- dtype detection (bf16 vs fp32 wire format) ----------
__global__ void detect_kernel(const unsigned short* __restrict__ x, int* flag) {
  __shared__ int cnt;
  if (threadIdx.x == 0) cnt = 0;
  __syncthreads();
  int c = 0;
  for (int i = threadIdx.x; i < 4096; i += 256) {
    if (((x[i] >> 7) & 0xFF) == 0xFF) c++;
  }
  atomicAdd(&cnt, c);
  __syncthreads();
  if (threadIdx.x == 0) *flag = (cnt > 0) ? 1 : 0;
}

// ---------- input canonicalization (vectorized) ----------
struct CvtArgs {
  const void* src[19];
  unsigned int n[19];
  unsigned int off[19];
};
__global__ __launch_bounds__(256) void convert_kernel(
    CvtArgs a, unsigned short* __restrict__ dst, const int* __restrict__ flag) {
  const int which = blockIdx.y;
  const unsigned int nn = a.n[which];
  unsigned short* d = dst + a.off[which];
  const unsigned int stride = gridDim.x * blockDim.x;
  const unsigned int idx = blockIdx.x * blockDim.x + threadIdx.x;
  const unsigned int ng = nn >> 3;
  if (*flag) {
    const float* s = (const float*)a.src[which];
    for (unsigned int g = idx; g < ng; g += stride) {
      const float4 f0 = ((const float4*)s)[g * 2];
      const float4 f1 = ((const float4*)s)[g * 2 + 1];
      ushort4 lo, hi;
      lo.x = f2bf(f0.x); lo.y = f2bf(f0.y); lo.z = f2bf(f0.z); lo.w = f2bf(f0.w);
      hi.x = f2bf(f1.x); hi.y = f2bf(f1.y); hi.z = f2bf(f1.z); hi.w = f2bf(f1.w);
      ((ushort4*)d)[g * 2] = lo;
      ((ushort4*)d)[g * 2 + 1] = hi;
    }
    for (unsigned int i = ng * 8 + idx; i < nn; i += stride) d[i] = f2bf(s[i]);
  } else {
    const unsigned short* s = (const unsigned short*)a.src[which];
    for (unsigned int g = idx; g < ng; g += stride)
      ((uint4*)d)[g] = ((const uint4*)s)[g];
    for (unsigned int i = ng * 8 + idx; i < nn; i += stride) d[i] = s[i];
  }
}

// ---------- bias table precompute: bias_full[h][n][m] fp32 ----------
__global__ __launch_bounds__(256) void bias_kernel(
    const unsigned short* __restrict__ cAb, const int* __restrict__ bias_idxs,
    float* __restrict__ bias_full) {
  const int h = blockIdx.x;
  for (int i = threadIdx.x; i < NTOK * NTOK; i += 256)
    bias_full[h * NTOK * NTOK + i] = bf2f(cAb[h * NTOK + bias_idxs[i]]);
}

// ---------- conv/BN table precompute: cwT[t][c] bf16, bn scale/shift fp32 ----------
__global__ __launch_bounds__(384) void prep_kernel(
    const unsigned short* __restrict__ cw, const unsigned short* __restrict__ bg,
    const unsigned short* __restrict__ bb, const unsigned short* __restrict__ bm,
    const unsigned short* __restrict__ bv,
    unsigned short* __restrict__ cwT, float* __restrict__ bnsc, float* __restrict__ bnsh) {
  const int c = threadIdx.x;
  const float sc = bf2f(bg[c]) * rsqrtf(bf2f(bv[c]) + EPS);
  bnsc[c] = sc;
  bnsh[c] = bf2f(bb[c]) - bf2f(bm[c]) * sc;
  #pragma unroll
  for (int t = 0; t < 9; ++t) cwT[t * CC + c] = cw[c * 9 + t];
}

// ---------- LayerNorm + window gather (pre-attention) ----------
__global__ __launch_bounds__(128) void ln_kernel(
    const unsigned short* __restrict__ x, const unsigned short* __restrict__ g,
    const unsigned short* __restrict__ b, unsigned short* __restrict__ out) {
  const int tid = threadIdx.x;
  int wi = blockIdx.y, n = blockIdx.x;
  int bb = wi >> 4, wb = wi & 15;
  int nh_i = wb >> 2, nw_i = wb & 3;
  int hs = n / 7, wsx = n - hs * 7;
  int l = nh_i * 196 + hs * 28 + nw_i * 7 + wsx;
  size_t src_row = (size_t)bb * LL + l;
  size_t dst_row = (size_t)wi * NTOK + n;
  const unsigned short* xr = x + src_row * CC;
  float vals[3]; float s = 0.f, sq = 0.f;
  for (int j = 0; j < 3; ++j) {
    vals[j] = bf2f(xr[tid + 128 * j]);
    s += vals[j]; sq += vals[j] * vals[j];
  }
  for (int off = 32; off; off >>= 1) { s += __shfl_xor(s, off); sq += __shfl_xor(sq, off); }
  __shared__ float red[4];
  const int wv = tid >> 6;
  if ((tid & 63) == 0) { red[wv] = s; red[2 + wv] = sq; }
  __syncthreads();
  float tot = red[0] + red[1], totq = red[2] + red[3];
  float mean = tot * (1.f / CC);
  float var = totq * (1.f / CC) - mean * mean;
  float inv = rsqrtf(var + EPS);
  unsigned short* orow = out + dst_row * CC;
  for (int j = 0; j < 3; ++j) {
    int c = tid + 128 * j;
    float y = (vals[j] - mean) * inv * bf2f(g[c]) + bf2f(b[c]);
    orow[c] = f2bf(y);
  }
}

// ---------- shared epilogue helpers ----------
enum { EP_PLAIN = 0, EP_GELU = 1, EP_WINRES = 2, EP_RES2 = 3 };

template <int EP>
__device__ __forceinline__ size_t ep_rowbase(int mr, int m_off, int N) {
  if (EP == EP_WINRES) {
    int wi = mr / 49; int nt2 = mr - wi * 49;
    int bb = wi >> 4; int wb = wi & 15;
    int nh_i = wb >> 2; int nw_i = wb & 3;
    int hs = nt2 / 7; int wsx = nt2 - hs * 7;
    int l = nh_i * 196 + hs * 28 + nw_i * 7 + wsx;
    return ((size_t)bb * LL + l) * CC;
  } else if (EP == EP_RES2) {
    return (size_t)(mr + m_off) * N;
  }
  return (size_t)mr * N;
}

template <int EP>
__device__ __forceinline__ void ep_store(
    void* outp, const unsigned short* res, size_t rowbase, int n,
    float v, int isf32) {
  if (EP == EP_GELU) {
    // gelu(x) = x * sigmoid(1.59576912x + 0.07135482x^3)
    const float t2 = v * (1.5957691216f + 0.0713548162f * v * v);
    v = __fdividef(v, 1.0f + __expf(-t2));
    ((unsigned short*)outp)[rowbase + n] = f2bf(v);
  } else if (EP == EP_WINRES) {
    size_t idx = rowbase + n;
    v += bf2f(res[idx]);
    ((unsigned short*)outp)[idx] = f2bf(v);
  } else if (EP == EP_RES2) {
    size_t idx = rowbase + n;
    v += bf2f(res[idx]);
    if (isf32) ((float*)outp)[idx] = v;
    else       ((unsigned short*)outp)[idx] = f2bf(v);
  } else {
    ((unsigned short*)outp)[rowbase + n] = f2bf(v);
  }
}

// ---------- GEMM-128: 128x128 tile, 4 waves, 4x4 acc, BK=32 (R6 proven) ----------
// 3 LDS buffers (24 KB wait-free rotation... 3x8KB = 48KB -> 3 blocks/CU),
// depth-2 prefetch, counted vmcnt(4), ONE barrier per K-step.
// [R7 lesson: B direct-to-register regressed 127->185 us (latency-exposed
// per-lane loads); keep B in LDS via global_load_lds DMA.]
template <int EP>
__global__ __launch_bounds__(256) void gemm128(
    const unsigned short* __restrict__ A, const unsigned short* __restrict__ W,
    const unsigned short* __restrict__ bias, const unsigned short* __restrict__ res,
    void* __restrict__ outp, int K, int N, int m_off, const int* __restrict__ flagp,
    int Nt) {
  __shared__ __align__(16) unsigned short lds[3 * 8192];  // 3 x (A 128x32 + B 128x32)
  const int tid = threadIdx.x;
  const int lane = tid & 63;
  const int wave = tid >> 6;
  const int nwg = gridDim.x;
  const int id = blockIdx.x;
  const int q8 = nwg >> 3, r8 = nwg & 7;
  const int xcd = id & 7, rank = id >> 3;
  const int wgid = (xcd < r8 ? xcd * (q8 + 1) : r8 * (q8 + 1) + (xcd - r8) * q8) + rank;
  const int bm = (wgid / Nt) * 128;
  const int bn = (wgid - (wgid / Nt) * Nt) * 128;
  const int wm = (wave >> 1) * 64;
  const int wn = (wave & 1) * 64;
  const int srow = tid >> 2;
  const int sr15 = srow & 15;
  const int sp = (sr15 + (sr15 >> 2)) & 3;
  const int s_col = ((tid & 3) ^ sp) * 8;   // swizzled source col (shorts)
  const unsigned short* Ap0 = A + (size_t)(bm + srow) * K + s_col;
  const unsigned short* Wp0 = W + (size_t)(bn + srow) * K + s_col;
  const size_t rstep = (size_t)64 * K;
  f32x4 acc[4][4] = {};
  const int fr = lane & 15;
  const int quad = lane >> 4;
  const int nt = K >> 5;
  const int rp = (fr + (fr >> 2)) & 3;
  const int cg = (quad ^ rp) * 8;

  auto stage = [&](int bsel, int t) {
    const unsigned short* ap = Ap0 + (size_t)t * 32;
    const unsigned short* wp = Wp0 + (size_t)t * 32;
    unsigned short* al = lds + bsel * 8192 + tid * 8;
    unsigned short* bl = al + 4096;
    gl_lds16(ap, al);
    gl_lds16(ap + rstep, al + 2048);
    gl_lds16(wp, bl);
    gl_lds16(wp + rstep, bl + 2048);
  };

  stage(0, 0);
  stage(1, 1);
  int b = 0;
  for (int t = 0; t < nt; ++t) {
    if (t + 1 < nt) asm volatile("s_waitcnt vmcnt(4)" ::: "memory");
    else            asm volatile("s_waitcnt vmcnt(0)" ::: "memory");
    __builtin_amdgcn_s_barrier();            // tile t resident; prior reads retired by all
    __builtin_amdgcn_sched_barrier(0);
    if (t + 2 < nt) stage(b ? b - 1 : 2, t + 2);   // buf[(t+2)%3] == buf[(t-1)%3]
    const unsigned short* Ab = lds + b * 8192;
    const unsigned short* Bb = Ab + 4096;
    bf16x8 af[4], bfr[4];
    #pragma unroll
    for (int i = 0; i < 4; ++i) {
      af[i]  = *(const bf16x8*)(Ab + (wm + i * 16 + fr) * 32 + cg);
      bfr[i] = *(const bf16x8*)(Bb + (wn + i * 16 + fr) * 32 + cg);
    }
    #pragma unroll
    for (int i = 0; i < 4; ++i)
      #pragma unroll
      for (int j = 0; j < 4; ++j)
        acc[i][j] = __builtin_amdgcn_mfma_f32_16x16x32_bf16(af[i], bfr[j], acc[i][j], 0, 0, 0);
    asm volatile("s_waitcnt lgkmcnt(0)" ::: "memory");
    __builtin_amdgcn_sched_barrier(0);
    b = (b == 2) ? 0 : b + 1;
  }

  int isf32 = 0;
  if (EP == EP_RES2) isf32 = *flagp;
  const int qr = (lane >> 4) * 4;
  float bvs[4];
  #pragma unroll
  for (int tj = 0; tj < 4; ++tj) bvs[tj] = bf2f(bias[bn + wn + tj * 16 + fr]);
  #pragma unroll
  for (int ti = 0; ti < 4; ++ti) {
    #pragma unroll
    for (int r = 0; r < 4; ++r) {
      const int mr = bm + wm + ti * 16 + qr + r;
      const size_t rowbase = ep_rowbase<EP>(mr, m_off, N);
      #pragma unroll
      for (int tj = 0; tj < 4; ++tj) {
        const int n = bn + wn + tj * 16 + fr;
        ep_store<EP>(outp, res, rowbase, n, acc[ti][tj][r] + bvs[tj], isf32);
      }
    }
  }
}

// ---------- GEMM-256: 256x128 tile, 4 waves, wave-tile 64x128 (acc 4x8) ----------
// Same proven K-loop as gemm128 (BK=32, 3 buffers, depth-2, single barrier)
// but 2x MFMA per fixed per-iteration cost (barrier + ds_read latency chain
// was ~75% of R6's iteration wall) and FLOP/LDS-byte 32 -> 42.7.
// LDS 3 x (A 256x32 = 16KB + B 128x32 = 8KB) = 72 KB -> 2 blocks/CU
// (= R6's MEASURED average occupancy of ~8 waves/CU, so little lost).
// Stage = 6 gl_lds16/thread -> counted vmcnt(6) at depth 2.
template <int EP>
__global__ __launch_bounds__(256) void gemm256(
    const unsigned short* __restrict__ A, const unsigned short* __restrict__ W,
    const unsigned short* __restrict__ bias, const unsigned short* __restrict__ res,
    void* __restrict__ outp, int K, int N, int m_off, const int* __restrict__ flagp,
    int Nt) {
  __shared__ __align__(16) unsigned short lds[3 * 12288];  // 73728 B
  const int tid = threadIdx.x;
  const int lane = tid & 63;
  const int wave = tid >> 6;
  const int nwg = gridDim.x;
  const int id = blockIdx.x;
  const int q8 = nwg >> 3, r8 = nwg & 7;
  const int xcd = id & 7, rank = id >> 3;
  const int wgid = (xcd < r8 ? xcd * (q8 + 1) : r8 * (q8 + 1) + (xcd - r8) * q8) + rank;
  const int bm = (wgid / Nt) * 256;
  const int bn = (wgid - (wgid / Nt) * Nt) * 128;
  const int wm = wave * 64;                 // wave-tile 64(M) x 128(N)
  const int srow = tid >> 2;                // 0..63
  const int sr15 = srow & 15;
  const int sp = (sr15 + (sr15 >> 2)) & 3;
  const int s_col = ((tid & 3) ^ sp) * 8;
  const unsigned short* Ap0 = A + (size_t)(bm + srow) * K + s_col;
  const unsigned short* Wp0 = W + (size_t)(bn + srow) * K + s_col;
  const size_t rstep = (size_t)64 * K;
  f32x4 acc[4][8] = {};
  const int fr = lane & 15;
  const int quad = lane >> 4;
  const int nt = K >> 5;
  const int rp = (fr + (fr >> 2)) & 3;
  const int cg = (quad ^ rp) * 8;

  auto stage = [&](int bsel, int t) {
    const unsigned short* ap = Ap0 + (size_t)t * 32;
    const unsigned short* wp = Wp0 + (size_t)t * 32;
    unsigned short* al = lds + bsel * 12288 + tid * 8;
    unsigned short* bl = lds + bsel * 12288 + 8192 + tid * 8;
    gl_lds16(ap, al);                        // A rows   0- 63
    gl_lds16(ap + rstep, al + 2048);         // A rows  64-127
    gl_lds16(ap + 2 * rstep, al + 4096);     // A rows 128-191
    gl_lds16(ap + 3 * rstep, al + 6144);     // A rows 192-255
    gl_lds16(wp, bl);                        // B rows   0- 63
    gl_lds16(wp + rstep, bl + 2048);         // B rows  64-127
  };

  stage(0, 0);
  stage(1, 1);
  int b = 0;
  for (int t = 0; t < nt; ++t) {
    // outstanding at wait: stage(t):6 + stage(t+1):6 -> vmcnt(6) retires t
    if (t + 1 < nt) asm volatile("s_waitcnt vmcnt(6)" ::: "memory");
    else            asm volatile("s_waitcnt vmcnt(0)" ::: "memory");
    __builtin_amdgcn_s_barrier();
    __builtin_amdgcn_sched_barrier(0);
    if (t + 2 < nt) stage(b ? b - 1 : 2, t + 2);
    const unsigned short* Ab = lds + b * 12288;
    const unsigned short* Bb = Ab + 8192;
    bf16x8 af[4], bfr[8];
    #pragma unroll
    for (int i = 0; i < 4; ++i)
      af[i] = *(const bf16x8*)(Ab + (wm + i * 16 + fr) * 32 + cg);
    #pragma unroll
    for (int j = 0; j < 8; ++j)
      bfr[j] = *(const bf16x8*)(Bb + (j * 16 + fr) * 32 + cg);
    #pragma unroll
    for (int i = 0; i < 4; ++i)
      #pragma unroll
      for (int j = 0; j < 8; ++j)
        acc[i][j] = __builtin_amdgcn_mfma_f32_16x16x32_bf16(af[i], bfr[j], acc[i][j], 0, 0, 0);
    asm volatile("s_waitcnt lgkmcnt(0)" ::: "memory");
    __builtin_amdgcn_sched_barrier(0);
    b = (b == 2) ? 0 : b + 1;
  }

  int isf32 = 0;
  if (EP == EP_RES2) isf32 = *flagp;
  const int qr = (lane >> 4) * 4;
  float bvs[8];
  #pragma unroll
  for (int tj = 0; tj < 8; ++tj) bvs[tj] = bf2f(bias[bn + tj * 16 + fr]);
  #pragma unroll
  for (int ti = 0; ti < 4; ++ti) {
    #pragma unroll
    for (int r = 0; r < 4; ++r) {
      const int mr = bm + wm + ti * 16 + qr + r;
      const size_t rowbase = ep_rowbase<EP>(mr, m_off, N);
      #pragma unroll
      for (int tj = 0; tj < 8; ++tj) {
        const int n = bn + tj * 16 + fr;
        ep_store<EP>(outp, res, rowbase, n, acc[ti][tj][r] + bvs[tj], isf32);
      }
    }
  }
}

// ---------- MFMA windowed attention: one WAVE per (window, head) ----------
__global__ __launch_bounds__(64) void attn_mfma(
    const unsigned short* __restrict__ qkv, const float* __restrict__ bias_full,
    unsigned short* __restrict__ o, int wi_off) {
  __shared__ __align__(16) unsigned short Pl[64 * 72];
  __shared__ __align__(16) unsigned short vT[32 * 72];
  const int wi = blockIdx.x, h = blockIdx.y;
  const int lane = threadIdx.x;
  const int l15 = lane & 15;
  const int quad = lane >> 4;
  const unsigned short* base = qkv + (size_t)wi * NTOK * QKV_OUT + h * 96;

  bf16x8 qf[4], kf[4];
  #pragma unroll
  for (int i = 0; i < 4; ++i) {
    const int n = i * 16 + l15;
    if (n < NTOK) {
      const unsigned short* p = base + (size_t)n * QKV_OUT + quad * 8;
      qf[i] = *(const bf16x8*)(p);
      kf[i] = *(const bf16x8*)(p + 32);
    } else {
      qf[i] = (bf16x8)0; kf[i] = (bf16x8)0;
    }
  }

  for (int idx = lane; idx < 32 * 72; idx += 64) vT[idx] = 0;
  __syncthreads();
  for (int idx = lane; idx < NTOK * KD; idx += 64) {
    const int m = idx >> 5, d = idx & 31;
    vT[d * 72 + m] = base[(size_t)m * QKV_OUT + 64 + d];
  }

  f32x4 acc[4][4] = {};
  #pragma unroll
  for (int i = 0; i < 4; ++i)
    #pragma unroll
    for (int j = 0; j < 4; ++j)
      acc[i][j] = __builtin_amdgcn_mfma_f32_16x16x32_bf16(qf[i], kf[j], acc[i][j], 0, 0, 0);

  const float* bh = bias_full + h * NTOK * NTOK;
  float rinv[4][4];
  #pragma unroll
  for (int i = 0; i < 4; ++i) {
    #pragma unroll
    for (int r = 0; r < 4; ++r) {
      const int n = i * 16 + quad * 4 + r;
      float sv[4];
      #pragma unroll
      for (int j = 0; j < 4; ++j) {
        const int m = j * 16 + l15;
        float s = acc[i][j][r] * SCALE;
        if (n < NTOK && m < NTOK) s += bh[n * NTOK + m];
        if (m >= NTOK) s = -1e30f;
        sv[j] = s;
      }
      float mx = fmaxf(fmaxf(sv[0], sv[1]), fmaxf(sv[2], sv[3]));
      #pragma unroll
      for (int t = 1; t < 16; t <<= 1) mx = fmaxf(mx, __shfl_xor(mx, t));
      float sum = 0.f;
      #pragma unroll
      for (int j = 0; j < 4; ++j) {
        const float p = __expf(sv[j] - mx);
        sum += p;
        Pl[n * 72 + j * 16 + l15] = f2bf(p);
      }
      #pragma unroll
      for (int t = 1; t < 16; t <<= 1) sum += __shfl_xor(sum, t);
      rinv[i][r] = 1.f / sum;
    }
  }
  __syncthreads();

  f32x4 acc2[4][2] = {};
  #pragma unroll
  for (int kk = 0; kk < 2; ++kk) {
    bf16x8 pf[4], vf[2];
    #pragma unroll
    for (int i = 0; i < 4; ++i)
      pf[i] = *(const bf16x8*)(Pl + (i * 16 + l15) * 72 + kk * 32 + quad * 8);
    #pragma unroll
    for (int jd = 0; jd < 2; ++jd)
      vf[jd] = *(const bf16x8*)(vT + (jd * 16 + l15) * 72 + kk * 32 + quad * 8);
    #pragma unroll
    for (int i = 0; i < 4; ++i)
      #pragma unroll
      for (int jd = 0; jd < 2; ++jd)
        acc2[i][jd] = __builtin_amdgcn_mfma_f32_16x16x32_bf16(pf[i], vf[jd], acc2[i][jd], 0, 0, 0);
  }

  #pragma unroll
  for (int i = 0; i < 4; ++i) {
    #pragma unroll
    for (int r = 0; r < 4; ++r) {
      const int n = i * 16 + quad * 4 + r;
      if (n < NTOK) {
        const float ri = rinv[i][r];
        #pragma unroll
        for (int jd = 0; jd < 2; ++jd) {
          const int d = jd * 16 + l15;
          o[((size_t)(wi_off + wi) * NTOK + n) * CC + h * KD + d] = f2bf(acc2[i][jd][r] * ri);
        }
      }
    }
  }
}

// ---------- fused depthwise 3x3 conv + BN + LN_m ----------
__global__ __launch_bounds__(384) void conv_bn_ln(
    const unsigned short* __restrict__ x1, const unsigned short* __restrict__ cwT,
    const float* __restrict__ bnsc, const float* __restrict__ bnsh,
    const unsigned short* __restrict__ mg, const unsigned short* __restrict__ mb,
    unsigned short* __restrict__ x2, unsigned short* __restrict__ xm) {
  __shared__ float rs[8][48], rq[8][48];
  const int tid = threadIdx.x;
  const int pos = tid / 48;
  const int c8 = tid - pos * 48;
  const int c0 = c8 * 8;
  const int hw = blockIdx.x * 8 + pos;
  const int b = blockIdx.y;
  const int h = hw / 28, w = hw - h * 28;
  float acc[8] = {};
  #pragma unroll
  for (int t = 0; t < 9; ++t) {
    const int dh = t / 3 - 1, dw = t % 3 - 1;
    const int hh = h + dh, ww = w + dw;
    if (hh >= 0 && hh < 28 && ww >= 0 && ww < 28) {
      const uint4 xv = *(const uint4*)(x1 + ((size_t)b * LL + hh * 28 + ww) * CC + c0);
      const uint4 wv = *(const uint4*)(cwT + t * CC + c0);
      const unsigned short* xp = (const unsigned short*)&xv;
      const unsigned short* wp = (const unsigned short*)&wv;
      #pragma unroll
      for (int k = 0; k < 8; ++k) acc[k] += bf2f(xp[k]) * bf2f(wp[k]);
    }
  }
  const float4 sc0 = *(const float4*)(bnsc + c0);
  const float4 sc1 = *(const float4*)(bnsc + c0 + 4);
  const float4 sh0 = *(const float4*)(bnsh + c0);
  const float4 sh1 = *(const float4*)(bnsh + c0 + 4);
  float y[8];
  y[0] = acc[0] * sc0.x + sh0.x; y[1] = acc[1] * sc0.y + sh0.y;
  y[2] = acc[2] * sc0.z + sh0.z; y[3] = acc[3] * sc0.w + sh0.w;
  y[4] = acc[4] * sc1.x + sh1.x; y[5] = acc[5] * sc1.y + sh1.y;
  y[6] = acc[6] * sc1.z + sh1.z; y[7] = acc[7] * sc1.w + sh1.w;
  ushort4 pk0, pk1;
  pk0.x = f2bf(y[0]); pk0.y = f2bf(y[1]); pk0.z = f2bf(y[2]); pk0.w = f2bf(y[3]);
  pk1.x = f2bf(y[4]); pk1.y = f2bf(y[5]); pk1.z = f2bf(y[6]); pk1.w = f2bf(y[7]);
  const size_t row = ((size_t)b * LL + hw) * CC + c0;
  *(ushort4*)(x2 + row) = pk0;
  *(ushort4*)(x2 + row + 4) = pk1;
  float s = 0.f, q = 0.f;
  #pragma unroll
  for (int k = 0; k < 8; ++k) { s += y[k]; q += y[k] * y[k]; }
  rs[pos][c8] = s; rq[pos][c8] = q;
  __syncthreads();
  float tot = 0.f, tq = 0.f;
  #pragma unroll 8
  for (int i = 0; i < 48; ++i) { tot += rs[pos][i]; tq += rq[pos][i]; }
  const float mean = tot * (1.f / CC);
  const float var = tq * (1.f / CC) - mean * mean;
  const float inv = rsqrtf(var + EPS);
  const uint4 gv = *(const uint4*)(mg + c0);
  const uint4 bv = *(const uint4*)(mb + c0);
  const unsigned short* gp = (const unsigned short*)&gv;
  const unsigned short* bp = (const unsigned short*)&bv;
  ushort4 lo, hi;
  unsigned short outv[8];
  #pragma unroll
  for (int k = 0; k < 8; ++k)
    outv[k] = f2bf((y[k] - mean) * inv * bf2f(gp[k]) + bf2f(bp[k]));
  lo.x = outv[0]; lo.y = outv[1]; lo.z = outv[2]; lo.w = outv[3];
  hi.x = outv[4]; hi.y = outv[5]; hi.z = outv[6]; hi.w = outv[7];
  *(ushort4*)(xm + row) = lo;
  *(ushort4*)(xm + row + 4) = hi;
}

// ---------- launch ----------
extern "C" void kernel_launch(void* const* d_in, const int* in_sizes, int n_in,
                              void* d_out, int out_size, void* d_ws, size_t ws_size,
                              hipStream_t stream) {
  int* flag = (int*)d_ws;
  unsigned short* base = (unsigned short*)d_ws;

  CvtArgs args;
  size_t cur = 32;
  size_t off[19];
  for (int i = 0; i < 19; ++i) {
    off[i] = cur;
    args.src[i] = d_in[i];
    args.n[i] = (unsigned int)in_sizes[i];
    args.off[i] = (unsigned int)cur;
    cur += ((size_t)in_sizes[i] + 63) & ~(size_t)63;
  }
  const unsigned short* cx   = base + off[0];
  const unsigned short* cgA  = base + off[1];
  const unsigned short* cbA  = base + off[2];
  const unsigned short* cQw  = base + off[3];
  const unsigned short* cQb  = base + off[4];
  const unsigned short* cAb  = base + off[5];
  const unsigned short* cPw  = base + off[6];
  const unsigned short* cPb  = base + off[7];
  const unsigned short* cCw  = base + off[8];
  const unsigned short* cBg  = base + off[9];
  const unsigned short* cBb  = base + off[10];
  const unsigned short* cBm  = base + off[11];
  const unsigned short* cBv  = base + off[12];
  const unsigned short* cMg  = base + off[13];
  const unsigned short* cMb  = base + off[14];
  const unsigned short* cF1w = base + off[15];
  const unsigned short* cF1b = base + off[16];
  const unsigned short* cF2w = base + off[17];
  const unsigned short* cF2b = base + off[18];
  const int* bias_idxs = (const int*)d_in[19];

  const size_t SZ = (size_t)MTOT * CC;             // 19267584 elems
  const size_t need_full_bytes =
      (cur + SZ + (size_t)MTOT * HID) * 2 + 512 * 1024;
  const int nchunk = (ws_size >= need_full_bytes) ? 1 : 2;
  const int MC = MTOT / nchunk;                    // GEMM rows per chunk
  const int WC = 1024 / nchunk;                    // windows per chunk
  const size_t buf2_cap = (size_t)MC * HID;

  unsigned short* o_buf = base + cur;               // attn out o; later xm
  unsigned short* buf2  = o_buf + SZ;               // qkv chunk / h chunk
  unsigned short* x2    = base + off[0];            // conv+BN out overwrites spent cx
  float* bias_full = (float*)(buf2 + buf2_cap);     // [12][49][49] f32
  unsigned short* cwT = (unsigned short*)(bias_full + 12 * NTOK * NTOK);  // [9][384] bf16
  float* bnsc = (float*)(cwT + 9 * CC);
  float* bnsh = bnsc + CC;

  unsigned short* xn = (unsigned short*)d_out;

  // 0. dtype detect + canonicalize + tables
  detect_kernel<<<1, 256, 0, stream>>>((const unsigned short*)d_in[0], flag);
  convert_kernel<<<dim3(512, 19), 256, 0, stream>>>(args, base, flag);
  bias_kernel<<<NHEAD, 256, 0, stream>>>(cAb, bias_idxs, bias_full);
  prep_kernel<<<1, 384, 0, stream>>>(cCw, cBg, cBb, cBm, cBv, cwT, bnsc, bnsh);

  // 1. window partition + LN_a -> xn (d_out)
  ln_kernel<<<dim3(49, 1024), 128, 0, stream>>>(cx, cgA, cbA, xn);

  // 2+3. qkv projection + MFMA attention
  for (int c = 0; c < nchunk; ++c) {
    gemm128<EP_PLAIN><<<(MC / 128) * (QKV_OUT / 128), 256, 0, stream>>>(
        xn + (size_t)c * MC * CC, cQw, cQb, nullptr, buf2, CC, QKV_OUT, 0, nullptr,
        QKV_OUT / 128);
    attn_mfma<<<dim3(WC, NHEAD), 64, 0, stream>>>(buf2, bias_full, o_buf, c * WC);
  }

  // 4. proj + un-window + residual(x) -> x1 (d_out)
  gemm128<EP_WINRES><<<(MTOT / 128) * (CC / 128), 256, 0, stream>>>(
      o_buf, cPw, cPb, cx, d_out, CC, CC, 0, nullptr, CC / 128);

  // 5. fused conv + BN + LN_m -> x2 (residual) and xm (o_buf, fc1 input)
  conv_bn_ln<<<dim3(98, BATCH), 384, 0, stream>>>(
      (const unsigned short*)d_out, cwT, bnsc, bnsh, cMg, cMb, x2, o_buf);

  // 6+7. MLP via gemm256 (256x128 tile, wave-tile 64x128); fc2 writes output
  for (int c = 0; c < nchunk; ++c) {
    gemm256<EP_GELU><<<(MC / 256) * (HID / 128), 256, 0, stream>>>(
        o_buf + (size_t)c * MC * CC, cF1w, cF1b, nullptr, buf2, CC, HID, 0, nullptr,
        HID / 128);
    gemm256<EP_RES2><<<(MC / 256) * (CC / 128), 256, 0, stream>>>(
        buf2, cF2w, cF2b, x2, d_out, HID, CC, c * MC, flag, CC / 128);
  }
}

// Round 9
// 679.450 us; speedup vs baseline: 1.1950x; 1.1437x over previous
//
#include <hip/hip_runtime.h>
#include <hip/hip_bf16.h>
#include <stdint.h>

// ---------- constants ----------
#define BATCH 64
#define CC 384
#define NHEAD 12
#define KD 32
#define NTOK 49
#define LL 784
#define MTOT 50176        // BATCH*LL = 1024 windows * 49
#define HID 1536
#define QKV_OUT 1152
#define SCALE 0.17677669529663687f
#define EPS 1e-5f

typedef __bf16 bf16x8 __attribute__((ext_vector_type(8)));
typedef float f32x4 __attribute__((ext_vector_type(4)));

__device__ __forceinline__ float bf2f(unsigned short u) {
  union { unsigned int u; float f; } cv; cv.u = ((unsigned int)u) << 16; return cv.f;
}
__device__ __forceinline__ unsigned short f2bf(float f) {
  union { float f; unsigned int u; } cv; cv.f = f;
  unsigned int r = cv.u + 0x7FFFu + ((cv.u >> 16) & 1u);
  return (unsigned short)(r >> 16);
}
__device__ __forceinline__ void gl_lds16(const unsigned short* g, unsigned short* l) {
  __builtin_amdgcn_global_load_lds(
      (const __attribute__((address_space(1))) unsigned int*)g,
      (__attribute__((address_space(3))) unsigned int*)l, 16, 0, 0);
}
// windowed row m (0..50175) -> flat row b*784+l
__device__ __forceinline__ int winrow(int m) {
  int wi = m / 49, nn = m - wi * 49;
  int bb = wi >> 4, wb = wi & 15;
  int hs = nn / 7, wsx = nn - hs * 7;
  return bb * LL + (wb >> 2) * 196 + hs * 28 + (wb & 3) * 7 + wsx;
}

// ---------- dtype detection (bf16 vs fp32 wire format) ----------
__global__ void detect_kernel(const unsigned short* __restrict__ x, int* flag) {
  __shared__ int cnt;
  if (threadIdx.x == 0) cnt = 0;
  __syncthreads();
  int c = 0;
  for (int i = threadIdx.x; i < 4096; i += 256) {
    if (((x[i] >> 7) & 0xFF) == 0xFF) c++;
  }
  atomicAdd(&cnt, c);
  __syncthreads();
  if (threadIdx.x == 0) *flag = (cnt > 0) ? 1 : 0;
}

// ---------- input canonicalization (vectorized) ----------
struct CvtArgs {
  const void* src[19];
  unsigned int n[19];
  unsigned int off[19];
};
__global__ __launch_bounds__(256) void convert_kernel(
    CvtArgs a, unsigned short* __restrict__ dst, const int* __restrict__ flag) {
  const int which = blockIdx.y;
  const unsigned int nn = a.n[which];
  unsigned short* d = dst + a.off[which];
  const unsigned int stride = gridDim.x * blockDim.x;
  const unsigned int idx = blockIdx.x * blockDim.x + threadIdx.x;
  const unsigned int ng = nn >> 3;
  if (*flag) {
    const float* s = (const float*)a.src[which];
    for (unsigned int g = idx; g < ng; g += stride) {
      const float4 f0 = ((const float4*)s)[g * 2];
      const float4 f1 = ((const float4*)s)[g * 2 + 1];
      ushort4 lo, hi;
      lo.x = f2bf(f0.x); lo.y = f2bf(f0.y); lo.z = f2bf(f0.z); lo.w = f2bf(f0.w);
      hi.x = f2bf(f1.x); hi.y = f2bf(f1.y); hi.z = f2bf(f1.z); hi.w = f2bf(f1.w);
      ((ushort4*)d)[g * 2] = lo;
      ((ushort4*)d)[g * 2 + 1] = hi;
    }
    for (unsigned int i = ng * 8 + idx; i < nn; i += stride) d[i] = f2bf(s[i]);
  } else {
    const unsigned short* s = (const unsigned short*)a.src[which];
    for (unsigned int g = idx; g < ng; g += stride)
      ((uint4*)d)[g] = ((const uint4*)s)[g];
    for (unsigned int i = ng * 8 + idx; i < nn; i += stride) d[i] = s[i];
  }
}

// ---------- bias table precompute: bias_full[h][n][m] fp32 ----------
__global__ __launch_bounds__(256) void bias_kernel(
    const unsigned short* __restrict__ cAb, const int* __restrict__ bias_idxs,
    float* __restrict__ bias_full) {
  const int h = blockIdx.x;
  for (int i = threadIdx.x; i < NTOK * NTOK; i += 256)
    bias_full[h * NTOK * NTOK + i] = bf2f(cAb[h * NTOK + bias_idxs[i]]);
}

// ---------- conv/BN table precompute ----------
__global__ __launch_bounds__(384) void prep_kernel(
    const unsigned short* __restrict__ cw, const unsigned short* __restrict__ bg,
    const unsigned short* __restrict__ bb, const unsigned short* __restrict__ bm,
    const unsigned short* __restrict__ bv,
    unsigned short* __restrict__ cwT, float* __restrict__ bnsc, float* __restrict__ bnsh) {
  const int c = threadIdx.x;
  const float sc = bf2f(bg[c]) * rsqrtf(bf2f(bv[c]) + EPS);
  bnsc[c] = sc;
  bnsh[c] = bf2f(bb[c]) - bf2f(bm[c]) * sc;
  #pragma unroll
  for (int t = 0; t < 9; ++t) cwT[t * CC + c] = cw[c * 9 + t];
}

// ---------- LN weight folding: W2 = g.W (bf16), S[n]=sum(g.W), C[n]=sum(b.W)+bias2 ----------
// ln(x).W^T + bias2 = invs*(x.W2^T - mu*S) + C   (per row: mu, invs)
__global__ __launch_bounds__(384) void fold_kernel(
    const unsigned short* __restrict__ W, const unsigned short* __restrict__ g,
    const unsigned short* __restrict__ bvec, const unsigned short* __restrict__ b2,
    unsigned short* __restrict__ W2, float* __restrict__ S, float* __restrict__ C) {
  const int n = blockIdx.x, k = threadIdx.x;
  const float w = bf2f(W[(size_t)n * CC + k]);
  const float gw = bf2f(g[k]) * w;
  const unsigned short r = f2bf(gw);
  W2[(size_t)n * CC + k] = r;
  float s = bf2f(r);                 // sum the ROUNDED values the MFMA will see
  float c = bf2f(bvec[k]) * w;
  #pragma unroll
  for (int off = 32; off; off >>= 1) { s += __shfl_xor(s, off); c += __shfl_xor(c, off); }
  __shared__ float s6[6], c6[6];
  const int wv = k >> 6;
  if ((k & 63) == 0) { s6[wv] = s; c6[wv] = c; }
  __syncthreads();
  if (k == 0) {
    float st = 0.f, ct = 0.f;
    #pragma unroll
    for (int i = 0; i < 6; ++i) { st += s6[i]; ct += c6[i]; }
    S[n] = st; C[n] = ct + bf2f(b2[n]);
  }
}

// ---------- LN_a row stats (windowed order), no tensor materialization ----------
__global__ __launch_bounds__(128) void statsA_kernel(
    const unsigned short* __restrict__ x, float* __restrict__ muA, float* __restrict__ invA) {
  const int tid = threadIdx.x;
  const int wi = blockIdx.y, n = blockIdx.x;
  const int l = (((wi & 15) >> 2) * 196 + (n / 7) * 28 + (wi & 3) * 7 + (n % 7));
  const unsigned short* xr = x + ((size_t)(wi >> 4) * LL + l) * CC;
  float s = 0.f, sq = 0.f;
  #pragma unroll
  for (int j = 0; j < 3; ++j) {
    const float v = bf2f(xr[tid + 128 * j]);
    s += v; sq += v * v;
  }
  #pragma unroll
  for (int off = 32; off; off >>= 1) { s += __shfl_xor(s, off); sq += __shfl_xor(sq, off); }
  __shared__ float red[4];
  const int wv = tid >> 6;
  if ((tid & 63) == 0) { red[wv] = s; red[2 + wv] = sq; }
  __syncthreads();
  if (tid == 0) {
    const float tot = red[0] + red[1], totq = red[2] + red[3];
    const float mean = tot * (1.f / CC);
    const float var = totq * (1.f / CC) - mean * mean;
    muA[(size_t)wi * NTOK + n] = mean;
    invA[(size_t)wi * NTOK + n] = rsqrtf(var + EPS);
  }
}

// ---------- GEMM: 128x128 tile, 4 waves, 4x4 acc, BK=32 (R6 proven K-loop) ----------
// 3 LDS buffers (48 KB -> 3 blocks/CU), depth-2 prefetch, counted vmcnt(4),
// ONE barrier per K-step. [R7: B-in-reg regressed; R8: 256-tile regressed
// (VGPR 136 + 72KB LDS -> occupancy 8% collapse). This structure is the
// measured optimum of the family; improvements now come from the pipeline.]
// EP_QKV: A-rows window-GATHERED at staging (per-lane global src is legal for
// global_load_lds); epilogue applies folded LN_a: v = iv*acc - iv*mu*S + C.
// EP_GELU2: folded LN_m + gelu. EP_WINRES/EP_RES2 as before.
enum { EP_PLAIN = 0, EP_WINRES = 2, EP_RES2 = 3, EP_QKV = 4, EP_GELU2 = 5 };

template <int EP>
__global__ __launch_bounds__(256) void gemm128(
    const unsigned short* __restrict__ A, const unsigned short* __restrict__ W,
    const unsigned short* __restrict__ bias, const unsigned short* __restrict__ res,
    void* __restrict__ outp, int K, int N, int m_off, const int* __restrict__ flagp,
    int Nt, const float* __restrict__ muv, const float* __restrict__ invv,
    const float* __restrict__ snv, const float* __restrict__ cnv) {
  constexpr bool GATHER = (EP == EP_QKV);
  constexpr bool LNFOLD = (EP == EP_QKV || EP == EP_GELU2);
  __shared__ __align__(16) unsigned short lds[3 * 8192];  // 3 x (A 128x32 + B 128x32)
  const int tid = threadIdx.x;
  const int lane = tid & 63;
  const int wave = tid >> 6;
  // XCD-chunked bijective remap (m204), N-fastest tile order (R4 keep)
  const int nwg = gridDim.x;
  const int id = blockIdx.x;
  const int q8 = nwg >> 3, r8 = nwg & 7;
  const int xcd = id & 7, rank = id >> 3;
  const int wgid = (xcd < r8 ? xcd * (q8 + 1) : r8 * (q8 + 1) + (xcd - r8) * q8) + rank;
  const int bm = (wgid / Nt) * 128;
  const int bn = (wgid - (wgid / Nt) * Nt) * 128;
  const int wm = (wave >> 1) * 64;
  const int wn = (wave & 1) * 64;
  const int srow = tid >> 2;
  const int sr15 = srow & 15;
  const int sp = (sr15 + (sr15 >> 2)) & 3;
  const int s_col = ((tid & 3) ^ sp) * 8;   // swizzled source col (shorts)
  int rowA0, rowA1;
  if (GATHER) {
    rowA0 = winrow(bm + srow + m_off);
    rowA1 = winrow(bm + srow + 64 + m_off);
  } else {
    rowA0 = bm + srow; rowA1 = rowA0 + 64;
  }
  const unsigned short* ApA = A + (size_t)rowA0 * K + s_col;
  const unsigned short* ApB = A + (size_t)rowA1 * K + s_col;
  const unsigned short* Wp0 = W + (size_t)(bn + srow) * K + s_col;
  const size_t rstep = (size_t)64 * K;
  f32x4 acc[4][4] = {};
  const int fr = lane & 15;
  const int quad = lane >> 4;
  const int nt = K >> 5;
  const int rp = (fr + (fr >> 2)) & 3;
  const int cg = (quad ^ rp) * 8;

  auto stage = [&](int bsel, int t) {
    unsigned short* al = lds + bsel * 8192 + tid * 8;
    unsigned short* bl = al + 4096;
    gl_lds16(ApA + t * 32, al);
    gl_lds16(ApB + t * 32, al + 2048);
    gl_lds16(Wp0 + t * 32, bl);
    gl_lds16(Wp0 + t * 32 + rstep, bl + 2048);
  };

  stage(0, 0);
  stage(1, 1);
  int b = 0;
  for (int t = 0; t < nt; ++t) {
    if (t + 1 < nt) asm volatile("s_waitcnt vmcnt(4)" ::: "memory");
    else            asm volatile("s_waitcnt vmcnt(0)" ::: "memory");
    __builtin_amdgcn_s_barrier();            // tile t resident; prior reads retired by all
    __builtin_amdgcn_sched_barrier(0);
    if (t + 2 < nt) stage(b ? b - 1 : 2, t + 2);   // buf[(t+2)%3] == buf[(t-1)%3]
    const unsigned short* Ab = lds + b * 8192;
    const unsigned short* Bb = Ab + 4096;
    bf16x8 af[4], bfr[4];
    #pragma unroll
    for (int i = 0; i < 4; ++i) {
      af[i]  = *(const bf16x8*)(Ab + (wm + i * 16 + fr) * 32 + cg);
      bfr[i] = *(const bf16x8*)(Bb + (wn + i * 16 + fr) * 32 + cg);
    }
    #pragma unroll
    for (int i = 0; i < 4; ++i)
      #pragma unroll
      for (int j = 0; j < 4; ++j)
        acc[i][j] = __builtin_amdgcn_mfma_f32_16x16x32_bf16(af[i], bfr[j], acc[i][j], 0, 0, 0);
    asm volatile("s_waitcnt lgkmcnt(0)" ::: "memory");
    __builtin_amdgcn_sched_barrier(0);
    b = (b == 2) ? 0 : b + 1;
  }

  int isf32 = 0;
  if (EP == EP_RES2) isf32 = *flagp;
  const int qr = quad * 4;
  float s4[4], c4[4], bvs[4];
  #pragma unroll
  for (int tj = 0; tj < 4; ++tj) {
    const int n = bn + wn + tj * 16 + fr;
    if (LNFOLD) { s4[tj] = snv[n]; c4[tj] = cnv[n]; }
    else        { bvs[tj] = bf2f(bias[n]); }
  }
  #pragma unroll
  for (int ti = 0; ti < 4; ++ti) {
    #pragma unroll
    for (int r = 0; r < 4; ++r) {
      const int mr = bm + wm + ti * 16 + qr + r;
      float iv = 0.f, um = 0.f;
      if (LNFOLD) { iv = invv[mr + m_off]; um = muv[mr + m_off] * iv; }
      size_t rowbase;
      if (EP == EP_WINRES)      rowbase = (size_t)winrow(mr) * CC;
      else if (EP == EP_RES2)   rowbase = (size_t)(mr + m_off) * N;
      else                      rowbase = (size_t)mr * N;
      #pragma unroll
      for (int tj = 0; tj < 4; ++tj) {
        const int n = bn + wn + tj * 16 + fr;
        if (EP == EP_QKV) {
          const float v = iv * acc[ti][tj][r] - um * s4[tj] + c4[tj];
          ((unsigned short*)outp)[rowbase + n] = f2bf(v);
        } else if (EP == EP_GELU2) {
          float v = iv * acc[ti][tj][r] - um * s4[tj] + c4[tj];
          // gelu(x) = x * sigmoid(1.59576912x + 0.07135482x^3)
          const float t2 = v * (1.5957691216f + 0.0713548162f * v * v);
          v = __fdividef(v, 1.0f + __expf(-t2));
          ((unsigned short*)outp)[rowbase + n] = f2bf(v);
        } else if (EP == EP_WINRES) {
          const size_t idx = rowbase + n;
          float v = acc[ti][tj][r] + bvs[tj] + bf2f(res[idx]);
          ((unsigned short*)outp)[idx] = f2bf(v);
        } else if (EP == EP_RES2) {
          const size_t idx = rowbase + n;
          float v = acc[ti][tj][r] + bvs[tj] + bf2f(res[idx]);
          if (isf32) ((float*)outp)[idx] = v;
          else       ((unsigned short*)outp)[idx] = f2bf(v);
        } else {
          ((unsigned short*)outp)[rowbase + n] = f2bf(acc[ti][tj][r] + bvs[tj]);
        }
      }
    }
  }
}

// ---------- MFMA windowed attention: one WAVE per (window, head) ----------
__global__ __launch_bounds__(64) void attn_mfma(
    const unsigned short* __restrict__ qkv, const float* __restrict__ bias_full,
    unsigned short* __restrict__ o, int wi_off) {
  __shared__ __align__(16) unsigned short Pl[64 * 72];
  __shared__ __align__(16) unsigned short vT[32 * 72];
  const int wi = blockIdx.x, h = blockIdx.y;
  const int lane = threadIdx.x;
  const int l15 = lane & 15;
  const int quad = lane >> 4;
  const unsigned short* base = qkv + (size_t)wi * NTOK * QKV_OUT + h * 96;

  bf16x8 qf[4], kf[4];
  #pragma unroll
  for (int i = 0; i < 4; ++i) {
    const int n = i * 16 + l15;
    if (n < NTOK) {
      const unsigned short* p = base + (size_t)n * QKV_OUT + quad * 8;
      qf[i] = *(const bf16x8*)(p);
      kf[i] = *(const bf16x8*)(p + 32);
    } else {
      qf[i] = (bf16x8)0; kf[i] = (bf16x8)0;
    }
  }

  for (int idx = lane; idx < 32 * 72; idx += 64) vT[idx] = 0;
  __syncthreads();
  for (int idx = lane; idx < NTOK * KD; idx += 64) {
    const int m = idx >> 5, d = idx & 31;
    vT[d * 72 + m] = base[(size_t)m * QKV_OUT + 64 + d];
  }

  f32x4 acc[4][4] = {};
  #pragma unroll
  for (int i = 0; i < 4; ++i)
    #pragma unroll
    for (int j = 0; j < 4; ++j)
      acc[i][j] = __builtin_amdgcn_mfma_f32_16x16x32_bf16(qf[i], kf[j], acc[i][j], 0, 0, 0);

  const float* bh = bias_full + h * NTOK * NTOK;
  float rinv[4][4];
  #pragma unroll
  for (int i = 0; i < 4; ++i) {
    #pragma unroll
    for (int r = 0; r < 4; ++r) {
      const int n = i * 16 + quad * 4 + r;
      float sv[4];
      #pragma unroll
      for (int j = 0; j < 4; ++j) {
        const int m = j * 16 + l15;
        float s = acc[i][j][r] * SCALE;
        if (n < NTOK && m < NTOK) s += bh[n * NTOK + m];
        if (m >= NTOK) s = -1e30f;
        sv[j] = s;
      }
      float mx = fmaxf(fmaxf(sv[0], sv[1]), fmaxf(sv[2], sv[3]));
      #pragma unroll
      for (int t = 1; t < 16; t <<= 1) mx = fmaxf(mx, __shfl_xor(mx, t));
      float sum = 0.f;
      #pragma unroll
      for (int j = 0; j < 4; ++j) {
        const float p = __expf(sv[j] - mx);
        sum += p;
        Pl[n * 72 + j * 16 + l15] = f2bf(p);
      }
      #pragma unroll
      for (int t = 1; t < 16; t <<= 1) sum += __shfl_xor(sum, t);
      rinv[i][r] = 1.f / sum;
    }
  }
  __syncthreads();

  f32x4 acc2[4][2] = {};
  #pragma unroll
  for (int kk = 0; kk < 2; ++kk) {
    bf16x8 pf[4], vf[2];
    #pragma unroll
    for (int i = 0; i < 4; ++i)
      pf[i] = *(const bf16x8*)(Pl + (i * 16 + l15) * 72 + kk * 32 + quad * 8);
    #pragma unroll
    for (int jd = 0; jd < 2; ++jd)
      vf[jd] = *(const bf16x8*)(vT + (jd * 16 + l15) * 72 + kk * 32 + quad * 8);
    #pragma unroll
    for (int i = 0; i < 4; ++i)
      #pragma unroll
      for (int jd = 0; jd < 2; ++jd)
        acc2[i][jd] = __builtin_amdgcn_mfma_f32_16x16x32_bf16(pf[i], vf[jd], acc2[i][jd], 0, 0, 0);
  }

  #pragma unroll
  for (int i = 0; i < 4; ++i) {
    #pragma unroll
    for (int r = 0; r < 4; ++r) {
      const int n = i * 16 + quad * 4 + r;
      if (n < NTOK) {
        const float ri = rinv[i][r];
        #pragma unroll
        for (int jd = 0; jd < 2; ++jd) {
          const int d = jd * 16 + l15;
          o[((size_t)(wi_off + wi) * NTOK + n) * CC + h * KD + d] = f2bf(acc2[i][jd][r] * ri);
        }
      }
    }
  }
}

// ---------- fused depthwise 3x3 conv + BN + LN_m stats ----------
// Writes x2 (conv+BN bf16, residual for fc2) and muM/invM (LN_m row stats,
// consumed by fc1's folded-LN epilogue). The 38.5 MB xm tensor is GONE.
__global__ __launch_bounds__(384) void conv_bn_ln(
    const unsigned short* __restrict__ x1, const unsigned short* __restrict__ cwT,
    const float* __restrict__ bnsc, const float* __restrict__ bnsh,
    unsigned short* __restrict__ x2, float* __restrict__ muM, float* __restrict__ invM) {
  __shared__ float rs[8][48], rq[8][48];
  const int tid = threadIdx.x;
  const int pos = tid / 48;
  const int c8 = tid - pos * 48;
  const int c0 = c8 * 8;
  const int hw = blockIdx.x * 8 + pos;
  const int b = blockIdx.y;
  const int h = hw / 28, w = hw - h * 28;
  float acc[8] = {};
  #pragma unroll
  for (int t = 0; t < 9; ++t) {
    const int dh = t / 3 - 1, dw = t % 3 - 1;
    const int hh = h + dh, ww = w + dw;
    if (hh >= 0 && hh < 28 && ww >= 0 && ww < 28) {
      const uint4 xv = *(const uint4*)(x1 + ((size_t)b * LL + hh * 28 + ww) * CC + c0);
      const uint4 wv = *(const uint4*)(cwT + t * CC + c0);
      const unsigned short* xp = (const unsigned short*)&xv;
      const unsigned short* wp = (const unsigned short*)&wv;
      #pragma unroll
      for (int k = 0; k < 8; ++k) acc[k] += bf2f(xp[k]) * bf2f(wp[k]);
    }
  }
  const float4 sc0 = *(const float4*)(bnsc + c0);
  const float4 sc1 = *(const float4*)(bnsc + c0 + 4);
  const float4 sh0 = *(const float4*)(bnsh + c0);
  const float4 sh1 = *(const float4*)(bnsh + c0 + 4);
  float y[8];
  y[0] = acc[0] * sc0.x + sh0.x; y[1] = acc[1] * sc0.y + sh0.y;
  y[2] = acc[2] * sc0.z + sh0.z; y[3] = acc[3] * sc0.w + sh0.w;
  y[4] = acc[4] * sc1.x + sh1.x; y[5] = acc[5] * sc1.y + sh1.y;
  y[6] = acc[6] * sc1.z + sh1.z; y[7] = acc[7] * sc1.w + sh1.w;
  unsigned short yr[8];
  #pragma unroll
  for (int k = 0; k < 8; ++k) yr[k] = f2bf(y[k]);
  ushort4 pk0, pk1;
  pk0.x = yr[0]; pk0.y = yr[1]; pk0.z = yr[2]; pk0.w = yr[3];
  pk1.x = yr[4]; pk1.y = yr[5]; pk1.z = yr[6]; pk1.w = yr[7];
  const size_t row = ((size_t)b * LL + hw) * CC + c0;
  *(ushort4*)(x2 + row) = pk0;
  *(ushort4*)(x2 + row + 4) = pk1;
  // LN stats over the ROUNDED values fc1's MFMA will actually consume
  float s = 0.f, q = 0.f;
  #pragma unroll
  for (int k = 0; k < 8; ++k) { const float v = bf2f(yr[k]); s += v; q += v * v; }
  rs[pos][c8] = s; rq[pos][c8] = q;
  __syncthreads();
  if (c8 == 0) {
    float tot = 0.f, tq = 0.f;
    #pragma unroll 8
    for (int i = 0; i < 48; ++i) { tot += rs[pos][i]; tq += rq[pos][i]; }
    const float mean = tot * (1.f / CC);
    const float var = tq * (1.f / CC) - mean * mean;
    muM[(size_t)b * LL + hw] = mean;
    invM[(size_t)b * LL + hw] = rsqrtf(var + EPS);
  }
}

// ---------- launch ----------
extern "C" void kernel_launch(void* const* d_in, const int* in_sizes, int n_in,
                              void* d_out, int out_size, void* d_ws, size_t ws_size,
                              hipStream_t stream) {
  int* flag = (int*)d_ws;
  unsigned short* base = (unsigned short*)d_ws;

  CvtArgs args;
  size_t cur = 32;
  size_t off[19];
  for (int i = 0; i < 19; ++i) {
    off[i] = cur;
    args.src[i] = d_in[i];
    args.n[i] = (unsigned int)in_sizes[i];
    args.off[i] = (unsigned int)cur;
    cur += ((size_t)in_sizes[i] + 63) & ~(size_t)63;
  }
  const unsigned short* cx   = base + off[0];
  const unsigned short* cgA  = base + off[1];
  const unsigned short* cbA  = base + off[2];
  const unsigned short* cQw  = base + off[3];
  const unsigned short* cQb  = base + off[4];
  const unsigned short* cAb  = base + off[5];
  const unsigned short* cPw  = base + off[6];
  const unsigned short* cPb  = base + off[7];
  const unsigned short* cCw  = base + off[8];
  const unsigned short* cBg  = base + off[9];
  const unsigned short* cBb  = base + off[10];
  const unsigned short* cBm  = base + off[11];
  const unsigned short* cBv  = base + off[12];
  const unsigned short* cMg  = base + off[13];
  const unsigned short* cMb  = base + off[14];
  const unsigned short* cF1w = base + off[15];
  const unsigned short* cF1b = base + off[16];
  const unsigned short* cF2w = base + off[17];
  const unsigned short* cF2b = base + off[18];
  const int* bias_idxs = (const int*)d_in[19];

  const size_t SZ = (size_t)MTOT * CC;             // 19267584 elems
  // tables: 4x f32[MTOT] stats + folded weights + s/c vectors
  const size_t tbl_bytes = 4 * (size_t)MTOT * 4 +
                           ((size_t)QKV_OUT + HID) * CC * 2 +
                           2 * ((size_t)QKV_OUT + HID) * 4 + 65536;
  const size_t need_full_bytes =
      (cur + SZ + (size_t)MTOT * HID) * 2 + tbl_bytes + 1024 * 1024;
  const int nchunk = (ws_size >= need_full_bytes) ? 1 : 2;
  const int MC = MTOT / nchunk;                    // GEMM rows per chunk
  const int WC = 1024 / nchunk;                    // windows per chunk
  const size_t buf2_cap = (size_t)MC * HID;

  unsigned short* o_buf = base + cur;               // attn out o
  unsigned short* buf2  = o_buf + SZ;               // qkv chunk / h chunk
  unsigned short* x2    = base + off[0];            // conv+BN out overwrites spent cx
  float* bias_full = (float*)(buf2 + buf2_cap);     // [12][49][49] f32
  unsigned short* cwT = (unsigned short*)(bias_full + 12 * NTOK * NTOK);  // [9][384] bf16
  float* bnsc = (float*)(cwT + 9 * CC);
  float* bnsh = bnsc + CC;
  float* muA  = bnsh + CC;
  float* invA = muA + MTOT;
  float* muM  = invA + MTOT;
  float* invM = muM + MTOT;
  float* sq   = invM + MTOT;          // [QKV_OUT]
  float* cq   = sq + QKV_OUT;
  float* sm   = cq + QKV_OUT;         // [HID]
  float* cm   = sm + HID;
  unsigned short* W2q = (unsigned short*)(cm + HID);       // [QKV_OUT][CC]
  unsigned short* W2m = W2q + (size_t)QKV_OUT * CC;        // [HID][CC]

  // 0. dtype detect + canonicalize + tables
  detect_kernel<<<1, 256, 0, stream>>>((const unsigned short*)d_in[0], flag);
  convert_kernel<<<dim3(512, 19), 256, 0, stream>>>(args, base, flag);
  bias_kernel<<<NHEAD, 256, 0, stream>>>(cAb, bias_idxs, bias_full);
  prep_kernel<<<1, 384, 0, stream>>>(cCw, cBg, cBb, cBm, cBv, cwT, bnsc, bnsh);
  fold_kernel<<<QKV_OUT, 384, 0, stream>>>(cQw, cgA, cbA, cQb, W2q, sq, cq);
  fold_kernel<<<HID, 384, 0, stream>>>(cF1w, cMg, cMb, cF1b, W2m, sm, cm);

  // 1. LN_a row stats (windowed order) — replaces the materialized LN tensor
  statsA_kernel<<<dim3(49, 1024), 128, 0, stream>>>(cx, muA, invA);

  // 2+3. fused LN_a + qkv projection (gathered A) + MFMA attention
  for (int c = 0; c < nchunk; ++c) {
    gemm128<EP_QKV><<<(MC / 128) * (QKV_OUT / 128), 256, 0, stream>>>(
        cx, W2q, nullptr, nullptr, buf2, CC, QKV_OUT, c * MC, nullptr,
        QKV_OUT / 128, muA, invA, sq, cq);
    attn_mfma<<<dim3(WC, NHEAD), 64, 0, stream>>>(buf2, bias_full, o_buf, c * WC);
  }

  // 4. proj + un-window + residual(x) -> x1 (d_out)
  gemm128<EP_WINRES><<<(MTOT / 128) * (CC / 128), 256, 0, stream>>>(
      o_buf, cPw, cPb, cx, d_out, CC, CC, 0, nullptr, CC / 128,
      nullptr, nullptr, nullptr, nullptr);

  // 5. fused conv + BN -> x2 (residual) + LN_m row stats (no xm tensor)
  conv_bn_ln<<<dim3(98, BATCH), 384, 0, stream>>>(
      (const unsigned short*)d_out, cwT, bnsc, bnsh, x2, muM, invM);

  // 6+7. MLP: fc1 = folded LN_m + gelu; fc2 writes final output
  for (int c = 0; c < nchunk; ++c) {
    gemm128<EP_GELU2><<<(MC / 128) * (HID / 128), 256, 0, stream>>>(
        x2 + (size_t)c * MC * CC, W2m, nullptr, nullptr, buf2, CC, HID, c * MC,
        nullptr, HID / 128, muM, invM, sm, cm);
    gemm128<EP_RES2><<<(MC / 128) * (CC / 128), 256, 0, stream>>>(
        buf2, cF2w, cF2b, x2, d_out, HID, CC, c * MC, flag, CC / 128,
        nullptr, nullptr, nullptr, nullptr);
  }
}

// Round 10
// 676.770 us; speedup vs baseline: 1.1997x; 1.0040x over previous
//
#include <hip/hip_runtime.h>
#include <hip/hip_bf16.h>
#include <stdint.h>

// ---------- constants ----------
#define BATCH 64
#define CC 384
#define NHEAD 12
#define KD 32
#define NTOK 49
#define LL 784
#define MTOT 50176        // BATCH*LL = 1024 windows * 49
#define HID 1536
#define QKV_OUT 1152
#define SCALE 0.17677669529663687f
#define EPS 1e-5f

typedef __bf16 bf16x8 __attribute__((ext_vector_type(8)));
typedef float f32x4 __attribute__((ext_vector_type(4)));

__device__ __forceinline__ float bf2f(unsigned short u) {
  union { unsigned int u; float f; } cv; cv.u = ((unsigned int)u) << 16; return cv.f;
}
__device__ __forceinline__ unsigned short f2bf(float f) {
  union { float f; unsigned int u; } cv; cv.f = f;
  unsigned int r = cv.u + 0x7FFFu + ((cv.u >> 16) & 1u);
  return (unsigned short)(r >> 16);
}
__device__ __forceinline__ void gl_lds16(const unsigned short* g, unsigned short* l) {
  __builtin_amdgcn_global_load_lds(
      (const __attribute__((address_space(1))) unsigned int*)g,
      (__attribute__((address_space(3))) unsigned int*)l, 16, 0, 0);
}

// ---------- dtype detection (bf16 vs fp32 wire format) ----------
__global__ void detect_kernel(const unsigned short* __restrict__ x, int* flag) {
  __shared__ int cnt;
  if (threadIdx.x == 0) cnt = 0;
  __syncthreads();
  int c = 0;
  for (int i = threadIdx.x; i < 4096; i += 256) {
    if (((x[i] >> 7) & 0xFF) == 0xFF) c++;
  }
  atomicAdd(&cnt, c);
  __syncthreads();
  if (threadIdx.x == 0) *flag = (cnt > 0) ? 1 : 0;
}

// ---------- input canonicalization (vectorized) ----------
struct CvtArgs {
  const void* src[19];
  unsigned int n[19];
  unsigned int off[19];
};
__global__ __launch_bounds__(256) void convert_kernel(
    CvtArgs a, unsigned short* __restrict__ dst, const int* __restrict__ flag) {
  const int which = blockIdx.y;
  const unsigned int nn = a.n[which];
  unsigned short* d = dst + a.off[which];
  const unsigned int stride = gridDim.x * blockDim.x;
  const unsigned int idx = blockIdx.x * blockDim.x + threadIdx.x;
  const unsigned int ng = nn >> 3;
  if (*flag) {
    const float* s = (const float*)a.src[which];
    for (unsigned int g = idx; g < ng; g += stride) {
      const float4 f0 = ((const float4*)s)[g * 2];
      const float4 f1 = ((const float4*)s)[g * 2 + 1];
      ushort4 lo, hi;
      lo.x = f2bf(f0.x); lo.y = f2bf(f0.y); lo.z = f2bf(f0.z); lo.w = f2bf(f0.w);
      hi.x = f2bf(f1.x); hi.y = f2bf(f1.y); hi.z = f2bf(f1.z); hi.w = f2bf(f1.w);
      ((ushort4*)d)[g * 2] = lo;
      ((ushort4*)d)[g * 2 + 1] = hi;
    }
    for (unsigned int i = ng * 8 + idx; i < nn; i += stride) d[i] = f2bf(s[i]);
  } else {
    const unsigned short* s = (const unsigned short*)a.src[which];
    for (unsigned int g = idx; g < ng; g += stride)
      ((uint4*)d)[g] = ((const uint4*)s)[g];
    for (unsigned int i = ng * 8 + idx; i < nn; i += stride) d[i] = s[i];
  }
}

// ---------- bias table precompute: bias_full[h][n][m] fp32 ----------
__global__ __launch_bounds__(256) void bias_kernel(
    const unsigned short* __restrict__ cAb, const int* __restrict__ bias_idxs,
    float* __restrict__ bias_full) {
  const int h = blockIdx.x;
  for (int i = threadIdx.x; i < NTOK * NTOK; i += 256)
    bias_full[h * NTOK * NTOK + i] = bf2f(cAb[h * NTOK + bias_idxs[i]]);
}

// ---------- conv/BN table precompute ----------
__global__ __launch_bounds__(384) void prep_kernel(
    const unsigned short* __restrict__ cw, const unsigned short* __restrict__ bg,
    const unsigned short* __restrict__ bb, const unsigned short* __restrict__ bm,
    const unsigned short* __restrict__ bv,
    unsigned short* __restrict__ cwT, float* __restrict__ bnsc, float* __restrict__ bnsh) {
  const int c = threadIdx.x;
  const float sc = bf2f(bg[c]) * rsqrtf(bf2f(bv[c]) + EPS);
  bnsc[c] = sc;
  bnsh[c] = bf2f(bb[c]) - bf2f(bm[c]) * sc;
  #pragma unroll
  for (int t = 0; t < 9; ++t) cwT[t * CC + c] = cw[c * 9 + t];
}

// ---------- LN weight folding: W2 = g.W (bf16), S[n]=sum(g.W), C[n]=sum(b.W)+bias2 ----------
// ln(x).W^T + bias2 = invs*(x.W2^T - mu*S) + C   (per row: mu, invs)
__global__ __launch_bounds__(384) void fold_kernel(
    const unsigned short* __restrict__ W, const unsigned short* __restrict__ g,
    const unsigned short* __restrict__ bvec, const unsigned short* __restrict__ b2,
    unsigned short* __restrict__ W2, float* __restrict__ S, float* __restrict__ C) {
  const int n = blockIdx.x, k = threadIdx.x;
  const float w = bf2f(W[(size_t)n * CC + k]);
  const float gw = bf2f(g[k]) * w;
  const unsigned short r = f2bf(gw);
  W2[(size_t)n * CC + k] = r;
  float s = bf2f(r);                 // sum the ROUNDED values the MFMA will see
  float c = bf2f(bvec[k]) * w;
  #pragma unroll
  for (int off = 32; off; off >>= 1) { s += __shfl_xor(s, off); c += __shfl_xor(c, off); }
  __shared__ float s6[6], c6[6];
  const int wv = k >> 6;
  if ((k & 63) == 0) { s6[wv] = s; c6[wv] = c; }
  __syncthreads();
  if (k == 0) {
    float st = 0.f, ct = 0.f;
    #pragma unroll
    for (int i = 0; i < 6; ++i) { st += s6[i]; ct += c6[i]; }
    S[n] = st; C[n] = ct + bf2f(b2[n]);
  }
}

// ---------- LN_a row stats, FLAT row order (contiguous reads) ----------
__global__ __launch_bounds__(128) void statsA_kernel(
    const unsigned short* __restrict__ x, float2* __restrict__ mui) {
  const int tid = threadIdx.x;
  const size_t row = (size_t)blockIdx.y * LL + blockIdx.x;
  const unsigned short* xr = x + row * CC;
  float s = 0.f, sq = 0.f;
  #pragma unroll
  for (int j = 0; j < 3; ++j) {
    const float v = bf2f(xr[tid + 128 * j]);
    s += v; sq += v * v;
  }
  #pragma unroll
  for (int off = 32; off; off >>= 1) { s += __shfl_xor(s, off); sq += __shfl_xor(sq, off); }
  __shared__ float red[4];
  const int wv = tid >> 6;
  if ((tid & 63) == 0) { red[wv] = s; red[2 + wv] = sq; }
  __syncthreads();
  if (tid == 0) {
    const float tot = red[0] + red[1], totq = red[2] + red[3];
    const float mean = tot * (1.f / CC);
    const float var = totq * (1.f / CC) - mean * mean;
    mui[row] = make_float2(mean, rsqrtf(var + EPS));
  }
}

// ---------- GEMM: 128x128 tile, 4 waves, 4x4 acc, BK=32 (R6 proven K-loop) ----------
// 3 LDS buffers (48 KB -> 3 blocks/CU), depth-2 prefetch, counted vmcnt(4),
// ONE barrier per K-step. [R7: B-in-reg regressed; R8: 256-tile regressed;
// R9: gather-in-staging regressed (scattered DMA rows). ALL GEMMs now run
// over FLAT contiguous rows; the window permutation lives only in attn,
// which reads/writes rows individually anyway.]
// EP_LNF:   folded LN epilogue (qkv):  v = iv*acc - iv*mu*S[n] + C[n]
// EP_GELU2: folded LN + fast gelu (fc1)
// EP_RES:   + residual, bf16 store (proj, flat rows)
// EP_RES2:  + residual, f32-or-bf16 by flag (fc2, final output)
enum { EP_RES = 2, EP_RES2 = 3, EP_LNF = 4, EP_GELU2 = 5 };

template <int EP>
__global__ __launch_bounds__(256) void gemm128(
    const unsigned short* __restrict__ A, const unsigned short* __restrict__ W,
    const unsigned short* __restrict__ bias, const unsigned short* __restrict__ res,
    void* __restrict__ outp, int K, int N, int m_off, const int* __restrict__ flagp,
    int Nt, const float2* __restrict__ mui,
    const float* __restrict__ snv, const float* __restrict__ cnv) {
  constexpr bool LNFOLD = (EP == EP_LNF || EP == EP_GELU2);
  __shared__ __align__(16) unsigned short lds[3 * 8192];  // 3 x (A 128x32 + B 128x32)
  const int tid = threadIdx.x;
  const int lane = tid & 63;
  const int wave = tid >> 6;
  // XCD-chunked bijective remap (m204), N-fastest tile order (R4 keep)
  const int nwg = gridDim.x;
  const int id = blockIdx.x;
  const int q8 = nwg >> 3, r8 = nwg & 7;
  const int xcd = id & 7, rank = id >> 3;
  const int wgid = (xcd < r8 ? xcd * (q8 + 1) : r8 * (q8 + 1) + (xcd - r8) * q8) + rank;
  const int bm = (wgid / Nt) * 128;
  const int bn = (wgid - (wgid / Nt) * Nt) * 128;
  const int wm = (wave >> 1) * 64;
  const int wn = (wave & 1) * 64;
  const int srow = tid >> 2;
  const int sr15 = srow & 15;
  const int sp = (sr15 + (sr15 >> 2)) & 3;
  const int s_col = ((tid & 3) ^ sp) * 8;   // swizzled source col (shorts)
  const unsigned short* Ap0 = A + (size_t)(bm + srow) * K + s_col;
  const unsigned short* Wp0 = W + (size_t)(bn + srow) * K + s_col;
  const size_t rstep = (size_t)64 * K;
  f32x4 acc[4][4] = {};
  const int fr = lane & 15;
  const int quad = lane >> 4;
  const int nt = K >> 5;
  const int rp = (fr + (fr >> 2)) & 3;
  const int cg = (quad ^ rp) * 8;

  auto stage = [&](int bsel, int t) {
    unsigned short* al = lds + bsel * 8192 + tid * 8;
    unsigned short* bl = al + 4096;
    gl_lds16(Ap0 + t * 32, al);
    gl_lds16(Ap0 + t * 32 + rstep, al + 2048);
    gl_lds16(Wp0 + t * 32, bl);
    gl_lds16(Wp0 + t * 32 + rstep, bl + 2048);
  };

  stage(0, 0);
  stage(1, 1);
  int b = 0;
  for (int t = 0; t < nt; ++t) {
    if (t + 1 < nt) asm volatile("s_waitcnt vmcnt(4)" ::: "memory");
    else            asm volatile("s_waitcnt vmcnt(0)" ::: "memory");
    __builtin_amdgcn_s_barrier();            // tile t resident; prior reads retired by all
    __builtin_amdgcn_sched_barrier(0);
    if (t + 2 < nt) stage(b ? b - 1 : 2, t + 2);   // buf[(t+2)%3] == buf[(t-1)%3]
    const unsigned short* Ab = lds + b * 8192;
    const unsigned short* Bb = Ab + 4096;
    bf16x8 af[4], bfr[4];
    #pragma unroll
    for (int i = 0; i < 4; ++i) {
      af[i]  = *(const bf16x8*)(Ab + (wm + i * 16 + fr) * 32 + cg);
      bfr[i] = *(const bf16x8*)(Bb + (wn + i * 16 + fr) * 32 + cg);
    }
    #pragma unroll
    for (int i = 0; i < 4; ++i)
      #pragma unroll
      for (int j = 0; j < 4; ++j)
        acc[i][j] = __builtin_amdgcn_mfma_f32_16x16x32_bf16(af[i], bfr[j], acc[i][j], 0, 0, 0);
    asm volatile("s_waitcnt lgkmcnt(0)" ::: "memory");
    __builtin_amdgcn_sched_barrier(0);
    b = (b == 2) ? 0 : b + 1;
  }

  int isf32 = 0;
  if (EP == EP_RES2) isf32 = *flagp;
  const int qr = quad * 4;
  float s4[4], c4[4], bvs[4];
  #pragma unroll
  for (int tj = 0; tj < 4; ++tj) {
    const int n = bn + wn + tj * 16 + fr;
    if (LNFOLD) { s4[tj] = snv[n]; c4[tj] = cnv[n]; }
    else        { bvs[tj] = bf2f(bias[n]); }
  }
  #pragma unroll
  for (int ti = 0; ti < 4; ++ti) {
    #pragma unroll
    for (int r = 0; r < 4; ++r) {
      const int mr = bm + wm + ti * 16 + qr + r;
      float iv = 0.f, um = 0.f;
      if (LNFOLD) {
        const float2 mi = mui[mr + m_off];
        iv = mi.y; um = mi.x * mi.y;
      }
      const size_t rowbase = (size_t)mr * N;
      #pragma unroll
      for (int tj = 0; tj < 4; ++tj) {
        const int n = bn + wn + tj * 16 + fr;
        if (EP == EP_LNF) {
          const float v = iv * acc[ti][tj][r] - um * s4[tj] + c4[tj];
          ((unsigned short*)outp)[rowbase + n] = f2bf(v);
        } else if (EP == EP_GELU2) {
          float v = iv * acc[ti][tj][r] - um * s4[tj] + c4[tj];
          // gelu(x) = x * sigmoid(1.59576912x + 0.07135482x^3)
          const float t2 = v * (1.5957691216f + 0.0713548162f * v * v);
          v = __fdividef(v, 1.0f + __expf(-t2));
          ((unsigned short*)outp)[rowbase + n] = f2bf(v);
        } else if (EP == EP_RES) {
          const size_t idx = rowbase + n;
          const float v = acc[ti][tj][r] + bvs[tj] + bf2f(res[idx]);
          ((unsigned short*)outp)[idx] = f2bf(v);
        } else {  // EP_RES2
          const size_t idx = rowbase + n;
          const float v = acc[ti][tj][r] + bvs[tj] + bf2f(res[idx]);
          if (isf32) ((float*)outp)[idx] = v;
          else       ((unsigned short*)outp)[idx] = f2bf(v);
        }
      }
    }
  }
}

// ---------- MFMA windowed attention: one WAVE per (window, head) ----------
// qkv and o are in FLAT row order; this kernel resolves the window->flat
// permutation per token (rows are read/written individually anyway).
__global__ __launch_bounds__(64) void attn_mfma(
    const unsigned short* __restrict__ qkv, const float* __restrict__ bias_full,
    unsigned short* __restrict__ o, int wi_off, int row_off) {
  __shared__ __align__(16) unsigned short Pl[64 * 72];
  __shared__ __align__(16) unsigned short vT[32 * 72];
  const int wi = wi_off + blockIdx.x, h = blockIdx.y;
  const int lane = threadIdx.x;
  const int l15 = lane & 15;
  const int quad = lane >> 4;
  // window -> flat row base pieces
  const int bb = wi >> 4, wb = wi & 15;
  const int wrow0 = bb * LL + (wb >> 2) * 196 + (wb & 3) * 7;
  auto flatrow = [&](int n) {
    const int h7 = n / 7;
    return wrow0 + h7 * 28 + (n - h7 * 7);
  };

  bf16x8 qf[4], kf[4];
  #pragma unroll
  for (int i = 0; i < 4; ++i) {
    const int n = i * 16 + l15;
    if (n < NTOK) {
      const unsigned short* p =
          qkv + (size_t)(flatrow(n) - row_off) * QKV_OUT + h * 96 + quad * 8;
      qf[i] = *(const bf16x8*)(p);
      kf[i] = *(const bf16x8*)(p + 32);
    } else {
      qf[i] = (bf16x8)0; kf[i] = (bf16x8)0;
    }
  }

  for (int idx = lane; idx < 32 * 72; idx += 64) vT[idx] = 0;
  __syncthreads();
  for (int idx = lane; idx < NTOK * KD; idx += 64) {
    const int m = idx >> 5, d = idx & 31;
    vT[d * 72 + m] = qkv[(size_t)(flatrow(m) - row_off) * QKV_OUT + h * 96 + 64 + d];
  }

  f32x4 acc[4][4] = {};
  #pragma unroll
  for (int i = 0; i < 4; ++i)
    #pragma unroll
    for (int j = 0; j < 4; ++j)
      acc[i][j] = __builtin_amdgcn_mfma_f32_16x16x32_bf16(qf[i], kf[j], acc[i][j], 0, 0, 0);

  const float* bh = bias_full + h * NTOK * NTOK;
  float rinv[4][4];
  #pragma unroll
  for (int i = 0; i < 4; ++i) {
    #pragma unroll
    for (int r = 0; r < 4; ++r) {
      const int n = i * 16 + quad * 4 + r;
      float sv[4];
      #pragma unroll
      for (int j = 0; j < 4; ++j) {
        const int m = j * 16 + l15;
        float s = acc[i][j][r] * SCALE;
        if (n < NTOK && m < NTOK) s += bh[n * NTOK + m];
        if (m >= NTOK) s = -1e30f;
        sv[j] = s;
      }
      float mx = fmaxf(fmaxf(sv[0], sv[1]), fmaxf(sv[2], sv[3]));
      #pragma unroll
      for (int t = 1; t < 16; t <<= 1) mx = fmaxf(mx, __shfl_xor(mx, t));
      float sum = 0.f;
      #pragma unroll
      for (int j = 0; j < 4; ++j) {
        const float p = __expf(sv[j] - mx);
        sum += p;
        Pl[n * 72 + j * 16 + l15] = f2bf(p);
      }
      #pragma unroll
      for (int t = 1; t < 16; t <<= 1) sum += __shfl_xor(sum, t);
      rinv[i][r] = 1.f / sum;
    }
  }
  __syncthreads();

  f32x4 acc2[4][2] = {};
  #pragma unroll
  for (int kk = 0; kk < 2; ++kk) {
    bf16x8 pf[4], vf[2];
    #pragma unroll
    for (int i = 0; i < 4; ++i)
      pf[i] = *(const bf16x8*)(Pl + (i * 16 + l15) * 72 + kk * 32 + quad * 8);
    #pragma unroll
    for (int jd = 0; jd < 2; ++jd)
      vf[jd] = *(const bf16x8*)(vT + (jd * 16 + l15) * 72 + kk * 32 + quad * 8);
    #pragma unroll
    for (int i = 0; i < 4; ++i)
      #pragma unroll
      for (int jd = 0; jd < 2; ++jd)
        acc2[i][jd] = __builtin_amdgcn_mfma_f32_16x16x32_bf16(pf[i], vf[jd], acc2[i][jd], 0, 0, 0);
  }

  #pragma unroll
  for (int i = 0; i < 4; ++i) {
    #pragma unroll
    for (int r = 0; r < 4; ++r) {
      const int n = i * 16 + quad * 4 + r;
      if (n < NTOK) {
        const float ri = rinv[i][r];
        const size_t orow = (size_t)flatrow(n) * CC + h * KD;
        #pragma unroll
        for (int jd = 0; jd < 2; ++jd) {
          const int d = jd * 16 + l15;
          o[orow + d] = f2bf(acc2[i][jd][r] * ri);
        }
      }
    }
  }
}

// ---------- fused depthwise 3x3 conv + BN + LN_m stats ----------
// Writes x2 (conv+BN bf16, residual for fc2) and mui (LN_m row stats float2,
// consumed by fc1's folded-LN epilogue). No xm tensor.
__global__ __launch_bounds__(384) void conv_bn_ln(
    const unsigned short* __restrict__ x1, const unsigned short* __restrict__ cwT,
    const float* __restrict__ bnsc, const float* __restrict__ bnsh,
    unsigned short* __restrict__ x2, float2* __restrict__ mui) {
  __shared__ float rs[8][48], rq[8][48];
  const int tid = threadIdx.x;
  const int pos = tid / 48;
  const int c8 = tid - pos * 48;
  const int c0 = c8 * 8;
  const int hw = blockIdx.x * 8 + pos;
  const int b = blockIdx.y;
  const int h = hw / 28, w = hw - h * 28;
  float acc[8] = {};
  #pragma unroll
  for (int t = 0; t < 9; ++t) {
    const int dh = t / 3 - 1, dw = t % 3 - 1;
    const int hh = h + dh, ww = w + dw;
    if (hh >= 0 && hh < 28 && ww >= 0 && ww < 28) {
      const uint4 xv = *(const uint4*)(x1 + ((size_t)b * LL + hh * 28 + ww) * CC + c0);
      const uint4 wv = *(const uint4*)(cwT + t * CC + c0);
      const unsigned short* xp = (const unsigned short*)&xv;
      const unsigned short* wp = (const unsigned short*)&wv;
      #pragma unroll
      for (int k = 0; k < 8; ++k) acc[k] += bf2f(xp[k]) * bf2f(wp[k]);
    }
  }
  const float4 sc0 = *(const float4*)(bnsc + c0);
  const float4 sc1 = *(const float4*)(bnsc + c0 + 4);
  const float4 sh0 = *(const float4*)(bnsh + c0);
  const float4 sh1 = *(const float4*)(bnsh + c0 + 4);
  float y[8];
  y[0] = acc[0] * sc0.x + sh0.x; y[1] = acc[1] * sc0.y + sh0.y;
  y[2] = acc[2] * sc0.z + sh0.z; y[3] = acc[3] * sc0.w + sh0.w;
  y[4] = acc[4] * sc1.x + sh1.x; y[5] = acc[5] * sc1.y + sh1.y;
  y[6] = acc[6] * sc1.z + sh1.z; y[7] = acc[7] * sc1.w + sh1.w;
  unsigned short yr[8];
  #pragma unroll
  for (int k = 0; k < 8; ++k) yr[k] = f2bf(y[k]);
  ushort4 pk0, pk1;
  pk0.x = yr[0]; pk0.y = yr[1]; pk0.z = yr[2]; pk0.w = yr[3];
  pk1.x = yr[4]; pk1.y = yr[5]; pk1.z = yr[6]; pk1.w = yr[7];
  const size_t row = ((size_t)b * LL + hw) * CC + c0;
  *(ushort4*)(x2 + row) = pk0;
  *(ushort4*)(x2 + row + 4) = pk1;
  // LN stats over the ROUNDED values fc1's MFMA will actually consume
  float s = 0.f, q = 0.f;
  #pragma unroll
  for (int k = 0; k < 8; ++k) { const float v = bf2f(yr[k]); s += v; q += v * v; }
  rs[pos][c8] = s; rq[pos][c8] = q;
  __syncthreads();
  if (c8 == 0) {
    float tot = 0.f, tq = 0.f;
    #pragma unroll 8
    for (int i = 0; i < 48; ++i) { tot += rs[pos][i]; tq += rq[pos][i]; }
    const float mean = tot * (1.f / CC);
    const float var = tq * (1.f / CC) - mean * mean;
    mui[(size_t)b * LL + hw] = make_float2(mean, rsqrtf(var + EPS));
  }
}

// ---------- launch ----------
extern "C" void kernel_launch(void* const* d_in, const int* in_sizes, int n_in,
                              void* d_out, int out_size, void* d_ws, size_t ws_size,
                              hipStream_t stream) {
  int* flag = (int*)d_ws;
  unsigned short* base = (unsigned short*)d_ws;

  CvtArgs args;
  size_t cur = 32;
  size_t off[19];
  for (int i = 0; i < 19; ++i) {
    off[i] = cur;
    args.src[i] = d_in[i];
    args.n[i] = (unsigned int)in_sizes[i];
    args.off[i] = (unsigned int)cur;
    cur += ((size_t)in_sizes[i] + 63) & ~(size_t)63;
  }
  const unsigned short* cx   = base + off[0];
  const unsigned short* cgA  = base + off[1];
  const unsigned short* cbA  = base + off[2];
  const unsigned short* cQw  = base + off[3];
  const unsigned short* cQb  = base + off[4];
  const unsigned short* cAb  = base + off[5];
  const unsigned short* cPw  = base + off[6];
  const unsigned short* cPb  = base + off[7];
  const unsigned short* cCw  = base + off[8];
  const unsigned short* cBg  = base + off[9];
  const unsigned short* cBb  = base + off[10];
  const unsigned short* cBm  = base + off[11];
  const unsigned short* cBv  = base + off[12];
  const unsigned short* cMg  = base + off[13];
  const unsigned short* cMb  = base + off[14];
  const unsigned short* cF1w = base + off[15];
  const unsigned short* cF1b = base + off[16];
  const unsigned short* cF2w = base + off[17];
  const unsigned short* cF2b = base + off[18];
  const int* bias_idxs = (const int*)d_in[19];

  const size_t SZ = (size_t)MTOT * CC;             // 19267584 elems
  const size_t tbl_bytes = 2 * (size_t)MTOT * 8 +
                           ((size_t)QKV_OUT + HID) * CC * 2 +
                           2 * ((size_t)QKV_OUT + HID) * 4 + 65536;
  const size_t need_full_bytes =
      (cur + SZ + (size_t)MTOT * HID) * 2 + tbl_bytes + 1024 * 1024;
  const int nchunk = (ws_size >= need_full_bytes) ? 1 : 2;
  const int MC = MTOT / nchunk;                    // GEMM rows per chunk
  const int WC = 1024 / nchunk;                    // windows per chunk
  const size_t buf2_cap = (size_t)MC * HID;

  unsigned short* o_buf = base + cur;               // attn out o (flat, full M)
  unsigned short* buf2  = o_buf + SZ;               // qkv chunk / h chunk
  unsigned short* x2    = base + off[0];            // conv+BN out overwrites spent cx
  float* bias_full = (float*)(buf2 + buf2_cap);     // [12][49][49] f32
  unsigned short* cwT = (unsigned short*)(bias_full + 12 * NTOK * NTOK);  // [9][384] bf16
  float* bnsc = (float*)(cwT + 9 * CC);
  float* bnsh = bnsc + CC;
  float2* muiA = (float2*)(bnsh + CC);
  float2* muiM = muiA + MTOT;
  float* sq   = (float*)(muiM + MTOT);   // [QKV_OUT]
  float* cq   = sq + QKV_OUT;
  float* sm   = cq + QKV_OUT;            // [HID]
  float* cm   = sm + HID;
  unsigned short* W2q = (unsigned short*)(cm + HID);       // [QKV_OUT][CC]
  unsigned short* W2m = W2q + (size_t)QKV_OUT * CC;        // [HID][CC]

  // 0. dtype detect + canonicalize + tables
  detect_kernel<<<1, 256, 0, stream>>>((const unsigned short*)d_in[0], flag);
  convert_kernel<<<dim3(512, 19), 256, 0, stream>>>(args, base, flag);
  bias_kernel<<<NHEAD, 256, 0, stream>>>(cAb, bias_idxs, bias_full);
  prep_kernel<<<1, 384, 0, stream>>>(cCw, cBg, cBb, cBm, cBv, cwT, bnsc, bnsh);
  fold_kernel<<<QKV_OUT, 384, 0, stream>>>(cQw, cgA, cbA, cQb, W2q, sq, cq);
  fold_kernel<<<HID, 384, 0, stream>>>(cF1w, cMg, cMb, cF1b, W2m, sm, cm);

  // 1. LN_a row stats, flat order (replaces the materialized LN tensor)
  statsA_kernel<<<dim3(LL, BATCH), 128, 0, stream>>>(cx, muiA);

  // 2+3. fused LN_a + qkv projection (FLAT rows) + attention (does the gather)
  for (int c = 0; c < nchunk; ++c) {
    gemm128<EP_LNF><<<(MC / 128) * (QKV_OUT / 128), 256, 0, stream>>>(
        cx + (size_t)c * MC * CC, W2q, nullptr, nullptr, buf2, CC, QKV_OUT, c * MC,
        nullptr, QKV_OUT / 128, muiA, sq, cq);
    attn_mfma<<<dim3(WC, NHEAD), 64, 0, stream>>>(
        buf2, bias_full, o_buf, c * WC, c * MC);
  }

  // 4. proj + residual(x) -> x1 (d_out), all flat rows
  gemm128<EP_RES><<<(MTOT / 128) * (CC / 128), 256, 0, stream>>>(
      o_buf, cPw, cPb, cx, d_out, CC, CC, 0, nullptr, CC / 128,
      nullptr, nullptr, nullptr);

  // 5. fused conv + BN -> x2 (residual) + LN_m row stats (no xm tensor)
  conv_bn_ln<<<dim3(98, BATCH), 384, 0, stream>>>(
      (const unsigned short*)d_out, cwT, bnsc, bnsh, x2, muiM);

  // 6+7. MLP: fc1 = folded LN_m + gelu; fc2 writes final output
  for (int c = 0; c < nchunk; ++c) {
    gemm128<EP_GELU2><<<(MC / 128) * (HID / 128), 256, 0, stream>>>(
        x2 + (size_t)c * MC * CC, W2m, nullptr, nullptr, buf2, CC, HID, c * MC,
        nullptr, HID / 128, muiM, sm, cm);
    gemm128<EP_RES2><<<(MC / 128) * (CC / 128), 256, 0, stream>>>(
        buf2, cF2w, cF2b, x2, d_out, HID, CC, c * MC, flag, CC / 128,
        nullptr, nullptr, nullptr);
  }
}

// Round 11
// 666.586 us; speedup vs baseline: 1.2181x; 1.0153x over previous
//
#include <hip/hip_runtime.h>
#include <hip/hip_bf16.h>
#include <stdint.h>

// ---------- constants ----------
#define BATCH 64
#define CC 384
#define NHEAD 12
#define KD 32
#define NTOK 49
#define LL 784
#define MTOT 50176        // BATCH*LL = 1024 windows * 49
#define HID 1536
#define QKV_OUT 1152
#define SCALE 0.17677669529663687f
#define EPS 1e-5f

typedef __bf16 bf16x8 __attribute__((ext_vector_type(8)));
typedef float f32x4 __attribute__((ext_vector_type(4)));

__device__ __forceinline__ float bf2f(unsigned short u) {
  union { unsigned int u; float f; } cv; cv.u = ((unsigned int)u) << 16; return cv.f;
}
__device__ __forceinline__ unsigned short f2bf(float f) {
  union { float f; unsigned int u; } cv; cv.f = f;
  unsigned int r = cv.u + 0x7FFFu + ((cv.u >> 16) & 1u);
  return (unsigned short)(r >> 16);
}
__device__ __forceinline__ void gl_lds16(const unsigned short* g, unsigned short* l) {
  __builtin_amdgcn_global_load_lds(
      (const __attribute__((address_space(1))) unsigned int*)g,
      (__attribute__((address_space(3))) unsigned int*)l, 16, 0, 0);
}

// ---------- dtype detection (bf16 vs fp32 wire format) ----------
__global__ void detect_kernel(const unsigned short* __restrict__ x, int* flag) {
  __shared__ int cnt;
  if (threadIdx.x == 0) cnt = 0;
  __syncthreads();
  int c = 0;
  for (int i = threadIdx.x; i < 4096; i += 256) {
    if (((x[i] >> 7) & 0xFF) == 0xFF) c++;
  }
  atomicAdd(&cnt, c);
  __syncthreads();
  if (threadIdx.x == 0) *flag = (cnt > 0) ? 1 : 0;
}

// ---------- input canonicalization (vectorized) ----------
struct CvtArgs {
  const void* src[19];
  unsigned int n[19];
  unsigned int off[19];
};
__global__ __launch_bounds__(256) void convert_kernel(
    CvtArgs a, unsigned short* __restrict__ dst, const int* __restrict__ flag) {
  const int which = blockIdx.y;
  const unsigned int nn = a.n[which];
  unsigned short* d = dst + a.off[which];
  const unsigned int stride = gridDim.x * blockDim.x;
  const unsigned int idx = blockIdx.x * blockDim.x + threadIdx.x;
  const unsigned int ng = nn >> 3;
  if (*flag) {
    const float* s = (const float*)a.src[which];
    for (unsigned int g = idx; g < ng; g += stride) {
      const float4 f0 = ((const float4*)s)[g * 2];
      const float4 f1 = ((const float4*)s)[g * 2 + 1];
      ushort4 lo, hi;
      lo.x = f2bf(f0.x); lo.y = f2bf(f0.y); lo.z = f2bf(f0.z); lo.w = f2bf(f0.w);
      hi.x = f2bf(f1.x); hi.y = f2bf(f1.y); hi.z = f2bf(f1.z); hi.w = f2bf(f1.w);
      ((ushort4*)d)[g * 2] = lo;
      ((ushort4*)d)[g * 2 + 1] = hi;
    }
    for (unsigned int i = ng * 8 + idx; i < nn; i += stride) d[i] = f2bf(s[i]);
  } else {
    const unsigned short* s = (const unsigned short*)a.src[which];
    for (unsigned int g = idx; g < ng; g += stride)
      ((uint4*)d)[g] = ((const uint4*)s)[g];
    for (unsigned int i = ng * 8 + idx; i < nn; i += stride) d[i] = s[i];
  }
}

// ---------- bias table precompute: bias_full[h][n][m] fp32 ----------
__global__ __launch_bounds__(256) void bias_kernel(
    const unsigned short* __restrict__ cAb, const int* __restrict__ bias_idxs,
    float* __restrict__ bias_full) {
  const int h = blockIdx.x;
  for (int i = threadIdx.x; i < NTOK * NTOK; i += 256)
    bias_full[h * NTOK * NTOK + i] = bf2f(cAb[h * NTOK + bias_idxs[i]]);
}

// ---------- conv/BN table precompute ----------
__global__ __launch_bounds__(384) void prep_kernel(
    const unsigned short* __restrict__ cw, const unsigned short* __restrict__ bg,
    const unsigned short* __restrict__ bb, const unsigned short* __restrict__ bm,
    const unsigned short* __restrict__ bv,
    unsigned short* __restrict__ cwT, float* __restrict__ bnsc, float* __restrict__ bnsh) {
  const int c = threadIdx.x;
  const float sc = bf2f(bg[c]) * rsqrtf(bf2f(bv[c]) + EPS);
  bnsc[c] = sc;
  bnsh[c] = bf2f(bb[c]) - bf2f(bm[c]) * sc;
  #pragma unroll
  for (int t = 0; t < 9; ++t) cwT[t * CC + c] = cw[c * 9 + t];
}

// ---------- LayerNorm, FLAT row order (fully coalesced; no permutation) ----------
__global__ __launch_bounds__(128) void ln_kernel(
    const unsigned short* __restrict__ x, const unsigned short* __restrict__ g,
    const unsigned short* __restrict__ b, unsigned short* __restrict__ out) {
  const int tid = threadIdx.x;
  const size_t row = (size_t)blockIdx.y * LL + blockIdx.x;
  const unsigned short* xr = x + row * CC;
  float vals[3]; float s = 0.f, sq = 0.f;
  #pragma unroll
  for (int j = 0; j < 3; ++j) {
    vals[j] = bf2f(xr[tid + 128 * j]);
    s += vals[j]; sq += vals[j] * vals[j];
  }
  #pragma unroll
  for (int off = 32; off; off >>= 1) { s += __shfl_xor(s, off); sq += __shfl_xor(sq, off); }
  __shared__ float red[4];
  const int wv = tid >> 6;
  if ((tid & 63) == 0) { red[wv] = s; red[2 + wv] = sq; }
  __syncthreads();
  const float tot = red[0] + red[1], totq = red[2] + red[3];
  const float mean = tot * (1.f / CC);
  const float var = totq * (1.f / CC) - mean * mean;
  const float inv = rsqrtf(var + EPS);
  unsigned short* orow = out + row * CC;
  #pragma unroll
  for (int j = 0; j < 3; ++j) {
    const int c = tid + 128 * j;
    orow[c] = f2bf((vals[j] - mean) * inv * bf2f(g[c]) + bf2f(b[c]));
  }
}

// ---------- GEMM: 128x128 tile, 4 waves, 4x4 acc, BK=32 ----------
// R11 A/B vs the R6 baseline (3-buf/48KB/depth-2/vmcnt(4), 657 us):
// 2 LDS buffers (32KB) -> occupancy cap moves from LDS (3 blocks/CU) to
// VGPR (4 blocks/CU, 16 waves): +33% TLP. Price: depth-1 prefetch, so the
// wait is vmcnt(0) - but staged loads get a full iteration (~1100 cyc) to
// land vs ~200-450 cyc L2/L3 latency (B panels L2-resident; fc2's A fits
// L3), and the 4th block hides the residue.
// Single barrier per K-step; WAR safe: stage(t+1) (issued after barrier
// B_t) overwrites buf[(t-1)&1], whose readers all retired (lgkmcnt(0))
// before reaching B_t. RAW safe: my vmcnt(0) + B_t => all waves' stage(t)
// DMA complete.
// [R7: B-in-reg regressed. R8: 256-tile regressed. R9/R10: LN-fold
// epilogues regressed (~+20 us net) - plain epilogues restored.]
// Grid: 1D, XCD-chunked bijective remap (m204) + N-fastest tile order.
enum { EP_PLAIN = 0, EP_GELU = 1, EP_RES = 2, EP_RES2 = 3 };

template <int EP>
__global__ __launch_bounds__(256) void gemm128(
    const unsigned short* __restrict__ A, const unsigned short* __restrict__ W,
    const unsigned short* __restrict__ bias, const unsigned short* __restrict__ res,
    void* __restrict__ outp, int K, int N, int m_off, const int* __restrict__ flagp,
    int Nt) {
  __shared__ __align__(16) unsigned short lds[2 * 8192];  // 2 x (A 128x32 + B 128x32)
  const int tid = threadIdx.x;
  const int lane = tid & 63;
  const int wave = tid >> 6;
  const int nwg = gridDim.x;
  const int id = blockIdx.x;
  const int q8 = nwg >> 3, r8 = nwg & 7;
  const int xcd = id & 7, rank = id >> 3;
  const int wgid = (xcd < r8 ? xcd * (q8 + 1) : r8 * (q8 + 1) + (xcd - r8) * q8) + rank;
  const int bm = (wgid / Nt) * 128;
  const int bn = (wgid - (wgid / Nt) * Nt) * 128;
  const int wm = (wave >> 1) * 64;
  const int wn = (wave & 1) * 64;
  const int srow = tid >> 2;
  const int sr15 = srow & 15;
  const int sp = (sr15 + (sr15 >> 2)) & 3;
  const int s_col = ((tid & 3) ^ sp) * 8;   // swizzled source col (shorts)
  const unsigned short* Ap0 = A + (size_t)(bm + srow) * K + s_col;
  const unsigned short* Wp0 = W + (size_t)(bn + srow) * K + s_col;
  const size_t rstep = (size_t)64 * K;
  f32x4 acc[4][4] = {};
  const int fr = lane & 15;
  const int quad = lane >> 4;
  const int nt = K >> 5;
  const int rp = (fr + (fr >> 2)) & 3;
  const int cg = (quad ^ rp) * 8;

  auto stage = [&](int bsel, int t) {
    unsigned short* al = lds + bsel * 8192 + tid * 8;
    unsigned short* bl = al + 4096;
    gl_lds16(Ap0 + t * 32, al);
    gl_lds16(Ap0 + t * 32 + rstep, al + 2048);
    gl_lds16(Wp0 + t * 32, bl);
    gl_lds16(Wp0 + t * 32 + rstep, bl + 2048);
  };

  stage(0, 0);
  for (int t = 0; t < nt; ++t) {
    const int cb = t & 1;
    asm volatile("s_waitcnt vmcnt(0)" ::: "memory");   // stage(t) complete (mine)
    __builtin_amdgcn_s_barrier();                      // ... and everyone else's
    __builtin_amdgcn_sched_barrier(0);
    if (t + 1 < nt) stage(cb ^ 1, t + 1);              // overwrites buf[(t-1)&1]: safe
    const unsigned short* Ab = lds + cb * 8192;
    const unsigned short* Bb = Ab + 4096;
    bf16x8 af[4], bfr[4];
    #pragma unroll
    for (int i = 0; i < 4; ++i) {
      af[i]  = *(const bf16x8*)(Ab + (wm + i * 16 + fr) * 32 + cg);
      bfr[i] = *(const bf16x8*)(Bb + (wn + i * 16 + fr) * 32 + cg);
    }
    #pragma unroll
    for (int i = 0; i < 4; ++i)
      #pragma unroll
      for (int j = 0; j < 4; ++j)
        acc[i][j] = __builtin_amdgcn_mfma_f32_16x16x32_bf16(af[i], bfr[j], acc[i][j], 0, 0, 0);
    asm volatile("s_waitcnt lgkmcnt(0)" ::: "memory");  // my reads of buf[t&1] retired
    __builtin_amdgcn_sched_barrier(0);
  }

  int isf32 = 0;
  if (EP == EP_RES2) isf32 = *flagp;
  const int qr = quad * 4;
  float bvs[4];
  #pragma unroll
  for (int tj = 0; tj < 4; ++tj) bvs[tj] = bf2f(bias[bn + wn + tj * 16 + fr]);
  #pragma unroll
  for (int ti = 0; ti < 4; ++ti) {
    #pragma unroll
    for (int r = 0; r < 4; ++r) {
      const int mr = bm + wm + ti * 16 + qr + r;
      const size_t rowbase = (size_t)mr * N;
      #pragma unroll
      for (int tj = 0; tj < 4; ++tj) {
        const int n = bn + wn + tj * 16 + fr;
        float v = acc[ti][tj][r] + bvs[tj];
        if (EP == EP_GELU) {
          // gelu(x) = x / (1 + exp2(t)), t = x*(-c1 - c2*x^2),
          // constants pre-multiplied by log2(e): c1=2.3021136, c2=0.10295398
          const float t2 = v * (-2.3021136f - 0.10295398f * v * v);
          v = __fdividef(v, 1.0f + __builtin_amdgcn_exp2f(t2));
          ((unsigned short*)outp)[rowbase + n] = f2bf(v);
        } else if (EP == EP_RES) {
          const size_t idx = rowbase + n;
          v += bf2f(res[idx]);
          ((unsigned short*)outp)[idx] = f2bf(v);
        } else if (EP == EP_RES2) {
          const size_t idx = rowbase + n;
          v += bf2f(res[idx]);
          if (isf32) ((float*)outp)[idx] = v;
          else       ((unsigned short*)outp)[idx] = f2bf(v);
        } else {
          ((unsigned short*)outp)[rowbase + n] = f2bf(v);
        }
      }
    }
  }
}

// ---------- MFMA windowed attention: one WAVE per (window, head) ----------
// qkv and o are in FLAT row order; this kernel resolves the window->flat
// permutation per token (rows are read/written individually anyway).
__global__ __launch_bounds__(64) void attn_mfma(
    const unsigned short* __restrict__ qkv, const float* __restrict__ bias_full,
    unsigned short* __restrict__ o, int wi_off, int row_off) {
  __shared__ __align__(16) unsigned short Pl[64 * 72];
  __shared__ __align__(16) unsigned short vT[32 * 72];
  const int wi = wi_off + blockIdx.x, h = blockIdx.y;
  const int lane = threadIdx.x;
  const int l15 = lane & 15;
  const int quad = lane >> 4;
  const int bb = wi >> 4, wb = wi & 15;
  const int wrow0 = bb * LL + (wb >> 2) * 196 + (wb & 3) * 7;
  auto flatrow = [&](int n) {
    const int h7 = n / 7;
    return wrow0 + h7 * 28 + (n - h7 * 7);
  };

  bf16x8 qf[4], kf[4];
  #pragma unroll
  for (int i = 0; i < 4; ++i) {
    const int n = i * 16 + l15;
    if (n < NTOK) {
      const unsigned short* p =
          qkv + (size_t)(flatrow(n) - row_off) * QKV_OUT + h * 96 + quad * 8;
      qf[i] = *(const bf16x8*)(p);
      kf[i] = *(const bf16x8*)(p + 32);
    } else {
      qf[i] = (bf16x8)0; kf[i] = (bf16x8)0;
    }
  }

  for (int idx = lane; idx < 32 * 72; idx += 64) vT[idx] = 0;
  __syncthreads();
  for (int idx = lane; idx < NTOK * KD; idx += 64) {
    const int m = idx >> 5, d = idx & 31;
    vT[d * 72 + m] = qkv[(size_t)(flatrow(m) - row_off) * QKV_OUT + h * 96 + 64 + d];
  }

  f32x4 acc[4][4] = {};
  #pragma unroll
  for (int i = 0; i < 4; ++i)
    #pragma unroll
    for (int j = 0; j < 4; ++j)
      acc[i][j] = __builtin_amdgcn_mfma_f32_16x16x32_bf16(qf[i], kf[j], acc[i][j], 0, 0, 0);

  const float* bh = bias_full + h * NTOK * NTOK;
  float rinv[4][4];
  #pragma unroll
  for (int i = 0; i < 4; ++i) {
    #pragma unroll
    for (int r = 0; r < 4; ++r) {
      const int n = i * 16 + quad * 4 + r;
      float sv[4];
      #pragma unroll
      for (int j = 0; j < 4; ++j) {
        const int m = j * 16 + l15;
        float s = acc[i][j][r] * SCALE;
        if (n < NTOK && m < NTOK) s += bh[n * NTOK + m];
        if (m >= NTOK) s = -1e30f;
        sv[j] = s;
      }
      float mx = fmaxf(fmaxf(sv[0], sv[1]), fmaxf(sv[2], sv[3]));
      #pragma unroll
      for (int t = 1; t < 16; t <<= 1) mx = fmaxf(mx, __shfl_xor(mx, t));
      float sum = 0.f;
      #pragma unroll
      for (int j = 0; j < 4; ++j) {
        const float p = __expf(sv[j] - mx);
        sum += p;
        Pl[n * 72 + j * 16 + l15] = f2bf(p);
      }
      #pragma unroll
      for (int t = 1; t < 16; t <<= 1) sum += __shfl_xor(sum, t);
      rinv[i][r] = 1.f / sum;
    }
  }
  __syncthreads();

  f32x4 acc2[4][2] = {};
  #pragma unroll
  for (int kk = 0; kk < 2; ++kk) {
    bf16x8 pf[4], vf[2];
    #pragma unroll
    for (int i = 0; i < 4; ++i)
      pf[i] = *(const bf16x8*)(Pl + (i * 16 + l15) * 72 + kk * 32 + quad * 8);
    #pragma unroll
    for (int jd = 0; jd < 2; ++jd)
      vf[jd] = *(const bf16x8*)(vT + (jd * 16 + l15) * 72 + kk * 32 + quad * 8);
    #pragma unroll
    for (int i = 0; i < 4; ++i)
      #pragma unroll
      for (int jd = 0; jd < 2; ++jd)
        acc2[i][jd] = __builtin_amdgcn_mfma_f32_16x16x32_bf16(pf[i], vf[jd], acc2[i][jd], 0, 0, 0);
  }

  #pragma unroll
  for (int i = 0; i < 4; ++i) {
    #pragma unroll
    for (int r = 0; r < 4; ++r) {
      const int n = i * 16 + quad * 4 + r;
      if (n < NTOK) {
        const float ri = rinv[i][r];
        const size_t orow = (size_t)flatrow(n) * CC + h * KD;
        #pragma unroll
        for (int jd = 0; jd < 2; ++jd) {
          const int d = jd * 16 + l15;
          o[orow + d] = f2bf(acc2[i][jd][r] * ri);
        }
      }
    }
  }
}

// ---------- fused depthwise 3x3 conv + BN + LN_m ----------
// Writes x2 (conv+BN, residual for fc2) AND xm (LayerNorm'd, fc1 input).
__global__ __launch_bounds__(384) void conv_bn_ln(
    const unsigned short* __restrict__ x1, const unsigned short* __restrict__ cwT,
    const float* __restrict__ bnsc, const float* __restrict__ bnsh,
    const unsigned short* __restrict__ mg, const unsigned short* __restrict__ mb,
    unsigned short* __restrict__ x2, unsigned short* __restrict__ xm) {
  __shared__ float rs[8][48], rq[8][48];
  const int tid = threadIdx.x;
  const int pos = tid / 48;
  const int c8 = tid - pos * 48;
  const int c0 = c8 * 8;
  const int hw = blockIdx.x * 8 + pos;
  const int b = blockIdx.y;
  const int h = hw / 28, w = hw - h * 28;
  float acc[8] = {};
  #pragma unroll
  for (int t = 0; t < 9; ++t) {
    const int dh = t / 3 - 1, dw = t % 3 - 1;
    const int hh = h + dh, ww = w + dw;
    if (hh >= 0 && hh < 28 && ww >= 0 && ww < 28) {
      const uint4 xv = *(const uint4*)(x1 + ((size_t)b * LL + hh * 28 + ww) * CC + c0);
      const uint4 wv = *(const uint4*)(cwT + t * CC + c0);
      const unsigned short* xp = (const unsigned short*)&xv;
      const unsigned short* wp = (const unsigned short*)&wv;
      #pragma unroll
      for (int k = 0; k < 8; ++k) acc[k] += bf2f(xp[k]) * bf2f(wp[k]);
    }
  }
  const float4 sc0 = *(const float4*)(bnsc + c0);
  const float4 sc1 = *(const float4*)(bnsc + c0 + 4);
  const float4 sh0 = *(const float4*)(bnsh + c0);
  const float4 sh1 = *(const float4*)(bnsh + c0 + 4);
  float y[8];
  y[0] = acc[0] * sc0.x + sh0.x; y[1] = acc[1] * sc0.y + sh0.y;
  y[2] = acc[2] * sc0.z + sh0.z; y[3] = acc[3] * sc0.w + sh0.w;
  y[4] = acc[4] * sc1.x + sh1.x; y[5] = acc[5] * sc1.y + sh1.y;
  y[6] = acc[6] * sc1.z + sh1.z; y[7] = acc[7] * sc1.w + sh1.w;
  ushort4 pk0, pk1;
  pk0.x = f2bf(y[0]); pk0.y = f2bf(y[1]); pk0.z = f2bf(y[2]); pk0.w = f2bf(y[3]);
  pk1.x = f2bf(y[4]); pk1.y = f2bf(y[5]); pk1.z = f2bf(y[6]); pk1.w = f2bf(y[7]);
  const size_t row = ((size_t)b * LL + hw) * CC + c0;
  *(ushort4*)(x2 + row) = pk0;
  *(ushort4*)(x2 + row + 4) = pk1;
  float s = 0.f, q = 0.f;
  #pragma unroll
  for (int k = 0; k < 8; ++k) { s += y[k]; q += y[k] * y[k]; }
  rs[pos][c8] = s; rq[pos][c8] = q;
  __syncthreads();
  float tot = 0.f, tq = 0.f;
  #pragma unroll 8
  for (int i = 0; i < 48; ++i) { tot += rs[pos][i]; tq += rq[pos][i]; }
  const float mean = tot * (1.f / CC);
  const float var = tq * (1.f / CC) - mean * mean;
  const float inv = rsqrtf(var + EPS);
  const uint4 gv = *(const uint4*)(mg + c0);
  const uint4 bv = *(const uint4*)(mb + c0);
  const unsigned short* gp = (const unsigned short*)&gv;
  const unsigned short* bp = (const unsigned short*)&bv;
  ushort4 lo, hi;
  unsigned short outv[8];
  #pragma unroll
  for (int k = 0; k < 8; ++k)
    outv[k] = f2bf((y[k] - mean) * inv * bf2f(gp[k]) + bf2f(bp[k]));
  lo.x = outv[0]; lo.y = outv[1]; lo.z = outv[2]; lo.w = outv[3];
  hi.x = outv[4]; hi.y = outv[5]; hi.z = outv[6]; hi.w = outv[7];
  *(ushort4*)(xm + row) = lo;
  *(ushort4*)(xm + row + 4) = hi;
}

// ---------- launch ----------
extern "C" void kernel_launch(void* const* d_in, const int* in_sizes, int n_in,
                              void* d_out, int out_size, void* d_ws, size_t ws_size,
                              hipStream_t stream) {
  int* flag = (int*)d_ws;
  unsigned short* base = (unsigned short*)d_ws;

  CvtArgs args;
  size_t cur = 32;
  size_t off[19];
  for (int i = 0; i < 19; ++i) {
    off[i] = cur;
    args.src[i] = d_in[i];
    args.n[i] = (unsigned int)in_sizes[i];
    args.off[i] = (unsigned int)cur;
    cur += ((size_t)in_sizes[i] + 63) & ~(size_t)63;
  }
  const unsigned short* cx   = base + off[0];
  const unsigned short* cgA  = base + off[1];
  const unsigned short* cbA  = base + off[2];
  const unsigned short* cQw  = base + off[3];
  const unsigned short* cQb  = base + off[4];
  const unsigned short* cAb  = base + off[5];
  const unsigned short* cPw  = base + off[6];
  const unsigned short* cPb  = base + off[7];
  const unsigned short* cCw  = base + off[8];
  const unsigned short* cBg  = base + off[9];
  const unsigned short* cBb  = base + off[10];
  const unsigned short* cBm  = base + off[11];
  const unsigned short* cBv  = base + off[12];
  const unsigned short* cMg  = base + off[13];
  const unsigned short* cMb  = base + off[14];
  const unsigned short* cF1w = base + off[15];
  const unsigned short* cF1b = base + off[16];
  const unsigned short* cF2w = base + off[17];
  const unsigned short* cF2b = base + off[18];
  const int* bias_idxs = (const int*)d_in[19];

  const size_t SZ = (size_t)MTOT * CC;             // 19267584 elems
  const size_t need_full_bytes =
      (cur + SZ + (size_t)MTOT * HID) * 2 + 1024 * 1024;
  const int nchunk = (ws_size >= need_full_bytes) ? 1 : 2;
  const int MC = MTOT / nchunk;                    // GEMM rows per chunk
  const int WC = 1024 / nchunk;                    // windows per chunk
  const size_t buf2_cap = (size_t)MC * HID;

  unsigned short* o_buf = base + cur;               // attn out o (flat); later xm
  unsigned short* buf2  = o_buf + SZ;               // qkv chunk / h chunk
  unsigned short* x2    = base + off[0];            // conv+BN out overwrites spent cx
  float* bias_full = (float*)(buf2 + buf2_cap);     // [12][49][49] f32
  unsigned short* cwT = (unsigned short*)(bias_full + 12 * NTOK * NTOK);  // [9][384] bf16
  float* bnsc = (float*)(cwT + 9 * CC);
  float* bnsh = bnsc + CC;

  unsigned short* xn = (unsigned short*)d_out;

  // 0. dtype detect + canonicalize + tables
  detect_kernel<<<1, 256, 0, stream>>>((const unsigned short*)d_in[0], flag);
  convert_kernel<<<dim3(512, 19), 256, 0, stream>>>(args, base, flag);
  bias_kernel<<<NHEAD, 256, 0, stream>>>(cAb, bias_idxs, bias_full);
  prep_kernel<<<1, 384, 0, stream>>>(cCw, cBg, cBb, cBm, cBv, cwT, bnsc, bnsh);

  // 1. LayerNorm_a, flat order -> xn (d_out)
  ln_kernel<<<dim3(LL, BATCH), 128, 0, stream>>>(cx, cgA, cbA, xn);

  // 2+3. qkv projection (flat rows) + attention (does the window gather)
  for (int c = 0; c < nchunk; ++c) {
    gemm128<EP_PLAIN><<<(MC / 128) * (QKV_OUT / 128), 256, 0, stream>>>(
        xn + (size_t)c * MC * CC, cQw, cQb, nullptr, buf2, CC, QKV_OUT, 0, nullptr,
        QKV_OUT / 128);
    attn_mfma<<<dim3(WC, NHEAD), 64, 0, stream>>>(
        buf2, bias_full, o_buf, c * WC, c * MC);
  }

  // 4. proj + residual(x) -> x1 (d_out), flat rows
  gemm128<EP_RES><<<(MTOT / 128) * (CC / 128), 256, 0, stream>>>(
      o_buf, cPw, cPb, cx, d_out, CC, CC, 0, nullptr, CC / 128);

  // 5. fused conv + BN + LN_m -> x2 (residual) and xm (o_buf, fc1 input)
  conv_bn_ln<<<dim3(98, BATCH), 384, 0, stream>>>(
      (const unsigned short*)d_out, cwT, bnsc, bnsh, cMg, cMb, x2, o_buf);

  // 6+7. MLP; fc2 writes final output
  for (int c = 0; c < nchunk; ++c) {
    gemm128<EP_GELU><<<(MC / 128) * (HID / 128), 256, 0, stream>>>(
        o_buf + (size_t)c * MC * CC, cF1w, cF1b, nullptr, buf2, CC, HID, 0, nullptr,
        HID / 128);
    gemm128<EP_RES2><<<(MC / 128) * (CC / 128), 256, 0, stream>>>(
        buf2, cF2w, cF2b, x2, d_out, HID, CC, c * MC, flag, CC / 128);
  }
}